// Round 7
// baseline (770.007 us; speedup 1.0000x reference)
//
#include <hip/hip_runtime.h>
#include <hip/hip_bf16.h>
#include <hip/hip_fp8.h>

#define DD   128
#define HH   8

typedef short bf16x8 __attribute__((ext_vector_type(8)));
typedef float f32x4  __attribute__((ext_vector_type(4)));
typedef float f32x2  __attribute__((ext_vector_type(2)));

__device__ __forceinline__ float b2f(unsigned short v){
  union { unsigned int u; float f; } x; x.u = ((unsigned int)v) << 16; return x.f;
}
__device__ __forceinline__ unsigned short f2b(float f){
  __hip_bfloat16 h = __float2bfloat16(f);
  return *(unsigned short*)&h;
}
__device__ __forceinline__ unsigned char f2f8(float x){
  __hip_fp8_e4m3 h(x);
  return h.__x;
}
__device__ __forceinline__ float f82f(unsigned char b){
  __hip_fp8_e4m3 h; h.__x = b;
  return (float)h;
}
// 4 fp8 bytes (one u32) -> 4 floats; HW packed cvt when available.
__device__ __forceinline__ void cvt4(unsigned int w, float* o){
#if defined(__has_builtin)
# if __has_builtin(__builtin_amdgcn_cvt_pk_f32_fp8)
  f32x2 lo = __builtin_amdgcn_cvt_pk_f32_fp8((int)w, false);
  f32x2 hi = __builtin_amdgcn_cvt_pk_f32_fp8((int)w, true);
  o[0]=lo[0]; o[1]=lo[1]; o[2]=hi[0]; o[3]=hi[1];
  return;
# endif
#endif
  o[0]=f82f(w&0xff); o[1]=f82f((w>>8)&0xff);
  o[2]=f82f((w>>16)&0xff); o[3]=f82f((w>>24)&0xff);
}
struct __align__(8) us4 { unsigned short x,y,z,w; };
struct __align__(16) us8 { unsigned short s[8]; };

__device__ __forceinline__ float gld(const void* p, size_t i, bool f32){
  if (f32) return ((const float*)p)[i];
  return b2f(((const unsigned short*)p)[i]);
}

// async global->LDS, 16B per lane (wave-uniform LDS base + lane*16)
__device__ __forceinline__ void gll16(const void* g, void* l){
  __builtin_amdgcn_global_load_lds(
      (const __attribute__((address_space(1))) unsigned int*)g,
      (__attribute__((address_space(3))) unsigned int*)l, 16, 0, 0);
}

// ALL weight blocks (8 tensors x NB matrices) -> bf16 TRANSPOSED staging, one launch.
struct WPtrs { const void* p[8]; };
__global__ __launch_bounds__(256) void w_repack16(
    WPtrs W, unsigned short* __restrict__ stage, int NBt,
    const int* __restrict__ dflag)
{
  const bool wf32 = (*dflag) != 0;
  int idx = blockIdx.x >> 6;
  int ti = idx / NBt, bi = idx - ti*NBt;
  size_t bo = (size_t)bi*DD*DD;
  int i = (blockIdx.x & 63)*256 + threadIdx.x;
  int k = i >> 7, n = i & 127;
  float x;
  if (wf32) x = ((const float*)W.p[ti])[bo + i];
  else      x = b2f(((const unsigned short*)W.p[ti])[bo + i]);
  stage[(size_t)idx*DD*DD + n*DD + k] = f2b(x);
}

enum { EPI_STORE=0, EPI_SCALE_CONST=1, EPI_RELU=3,
       EPI_RELU_RES=4, EPI_RELU_RES2=5 };

#define CPAD 132

// C[M,128] = epi( A[M,128] @ B[128,128] ), B bf16 TRANSPOSED ([n][k]).
// EPI_RELU_RES : C = relu(x) + Rb(bf16)                  [big Wo, OUTB=1]
// EPI_RELU_RES2: Cv = relu(x) f32; C2 = relu(x)+Rf (f32) [meta Wo, OUTB=0]
template<int EPI, bool INB, bool OUTB>
__global__ __launch_bounds__(256) void gemm128m(
    const void* __restrict__ Av, const unsigned short* __restrict__ Bt,
    void* __restrict__ Cv, int M,
    const unsigned short* __restrict__ Rb,
    const float* __restrict__ Rf, float* __restrict__ C2)
{
  __shared__ __align__(16) unsigned short Asb[64*128];
  __shared__ __align__(16) unsigned short Btb[16896];  // B: 32KB / C: 64x132 f32
  const int tid = threadIdx.x;
  const int wave = tid >> 6, lane = tid & 63;
  const int row0 = blockIdx.x * 64;

  if (INB){
    const char* Ab = (const char*)Av;
    int n4 = lane >> 4, c = lane & 15;
#pragma unroll
    for (int op=0; op<4; op++){
      int rA = wave*16 + op*4;
      int n = rA + n4;
      int gr = row0 + n; if (gr >= M) gr = M - 1;
      gll16(Ab + (size_t)gr*256 + ((size_t)((c ^ (n & 7)) << 4)), &Asb[rA*128]);
    }
  } else {
    const float* Af = (const float*)Av;
    int r = tid >> 2, cb = (tid & 3) * 32, rx = (r & 7) << 3;
    int gr = row0 + r;
#pragma unroll
    for (int j=0;j<8;j++){
      int cc = cb + j*4;
      float4 val = make_float4(0.f,0.f,0.f,0.f);
      if (gr < M) val = *(const float4*)(Af + (size_t)gr*DD + cc);
      us4 o; o.x=f2b(val.x); o.y=f2b(val.y); o.z=f2b(val.z); o.w=f2b(val.w);
      *(us4*)&Asb[r*128 + (cc ^ rx)] = o;
    }
  }
  {
    int n4 = lane >> 4, c = lane & 15;
#pragma unroll
    for (int op=0; op<8; op++){
      int rB = wave*32 + op*4;
      int n = rB + n4;
      gll16((const char*)Bt + (size_t)n*256 + ((size_t)((c ^ (n & 7)) << 4)),
            &Btb[rB*128]);
    }
  }
  __syncthreads();

  f32x4 acc[8];
#pragma unroll
  for (int t=0;t<8;t++) acc[t] = (f32x4){0.f,0.f,0.f,0.f};
  const int am = (lane & 15), kq = (lane >> 4) * 8, axr = (am & 7) << 3;
#pragma unroll
  for (int k0=0;k0<128;k0+=32){
    int xo = (k0 + kq) ^ axr;
    bf16x8 a = *(bf16x8*)&Asb[(wave*16 + am)*128 + xo];
#pragma unroll
    for (int t=0;t<8;t++){
      bf16x8 b = *(bf16x8*)&Btb[(t*16 + am)*128 + xo];
      acc[t] = __builtin_amdgcn_mfma_f32_16x16x32_bf16(a, b, acc[t], 0,0,0);
    }
  }
  __syncthreads();
  float* Cls = (float*)Btb;
  {
    int rr = wave*16 + (lane>>4)*4;
    int cc = lane & 15;
#pragma unroll
    for (int t=0;t<8;t++)
#pragma unroll
      for (int r=0;r<4;r++)
        Cls[(rr + r)*CPAD + t*16 + cc] = acc[t][r];
  }
  __syncthreads();

  {
    int r = tid >> 2, cb = (tid & 3) * 32;
    int gr = row0 + r;
    if (gr < M){
#pragma unroll
      for (int j=0;j<8;j++){
        int c = cb + j*4;
        float4 o = *(float4*)&Cls[r*CPAD + c];
        if (EPI == EPI_RELU_RES){
          us4 rb = *(const us4*)(Rb + (size_t)gr*DD + c);
          o.x=fmaxf(o.x,0.f)+b2f(rb.x); o.y=fmaxf(o.y,0.f)+b2f(rb.y);
          o.z=fmaxf(o.z,0.f)+b2f(rb.z); o.w=fmaxf(o.w,0.f)+b2f(rb.w);
        } else if (EPI == EPI_RELU_RES2){
          o.x=fmaxf(o.x,0.f); o.y=fmaxf(o.y,0.f); o.z=fmaxf(o.z,0.f); o.w=fmaxf(o.w,0.f);
          float4 rf = *(const float4*)(Rf + (size_t)gr*DD + c);
          *(float4*)(C2 + (size_t)gr*DD + c) =
              make_float4(o.x+rf.x, o.y+rf.y, o.z+rf.z, o.w+rf.w);
        }
        if (OUTB){
          us4 ob; ob.x=f2b(o.x); ob.y=f2b(o.y); ob.z=f2b(o.z); ob.w=f2b(o.w);
          *(us4*)((unsigned short*)Cv + (size_t)gr*DD + c) = ob;
        } else {
          *(float4*)((float*)Cv + (size_t)gr*DD + c) = o;
        }
      }
    }
  }
}

// Fused Q/K/V gemm body.
// FP8KV (big graph): outputs HEAD-MAJOR slices for XCD-affine edge_fused:
//   ph0 -> qh [8][M][16] bf16;  ph1/2 -> kvh [8][M][32] fp8 (k at 0, v at 16), x8 scale.
// !FP8KV (meta): node-major bf16, q scaled by svec.
template<int EPIQ, bool INB, bool FP8KV>
__device__ __forceinline__ void qkv_body(
    unsigned short* Asb, unsigned short* Btb, int blk,
    const void* __restrict__ Av,
    const unsigned short* __restrict__ Btq, const unsigned short* __restrict__ Btk,
    const unsigned short* __restrict__ Btv,
    void* __restrict__ Cq, void* __restrict__ Ck, int stK,
    void* __restrict__ Cvo, int stV, int M,
    const float* __restrict__ svec)
{
  const int tid = threadIdx.x;
  const int wave = tid >> 6, lane = tid & 63;
  const int row0 = blk * 64;

  if (INB){
    const char* Ab = (const char*)Av;
    int n4 = lane >> 4, c = lane & 15;
#pragma unroll
    for (int op=0; op<4; op++){
      int rA = wave*16 + op*4;
      int n = rA + n4;
      int gr = row0 + n; if (gr >= M) gr = M - 1;
      gll16(Ab + (size_t)gr*256 + ((size_t)((c ^ (n & 7)) << 4)), &Asb[rA*128]);
    }
  } else {
    const float* Af = (const float*)Av;
    int r = tid >> 2, cb = (tid & 3) * 32, rx = (r & 7) << 3;
    int gr = row0 + r;
#pragma unroll
    for (int j=0;j<8;j++){
      int cc = cb + j*4;
      float4 val = make_float4(0.f,0.f,0.f,0.f);
      if (gr < M) val = *(const float4*)(Af + (size_t)gr*DD + cc);
      us4 o; o.x=f2b(val.x); o.y=f2b(val.y); o.z=f2b(val.z); o.w=f2b(val.w);
      *(us4*)&Asb[r*128 + (cc ^ rx)] = o;
    }
  }

  const unsigned short* Bts[3] = {Btq, Btk, Btv};
  void* Cs[3] = {Cq, Ck, Cvo};
  const int sts[3] = {DD, stK, stV};
  const int am = (lane & 15), kq = (lane >> 4) * 8, axr = (am & 7) << 3;

  for (int ph=0; ph<3; ph++){
    {
      const unsigned short* Bt = Bts[ph];
      int n4 = lane >> 4, c = lane & 15;
#pragma unroll
      for (int op=0; op<8; op++){
        int rB = wave*32 + op*4;
        int n = rB + n4;
        gll16((const char*)Bt + (size_t)n*256 + ((size_t)((c ^ (n & 7)) << 4)),
              &Btb[rB*128]);
      }
    }
    __syncthreads();
    f32x4 acc[8];
#pragma unroll
    for (int t=0;t<8;t++) acc[t] = (f32x4){0.f,0.f,0.f,0.f};
#pragma unroll
    for (int k0=0;k0<128;k0+=32){
      int xo = (k0 + kq) ^ axr;
      bf16x8 a = *(bf16x8*)&Asb[(wave*16 + am)*128 + xo];
#pragma unroll
      for (int t=0;t<8;t++){
        bf16x8 b = *(bf16x8*)&Btb[(t*16 + am)*128 + xo];
        acc[t] = __builtin_amdgcn_mfma_f32_16x16x32_bf16(a, b, acc[t], 0,0,0);
      }
    }
    __syncthreads();
    float* Cls = (float*)Btb;
    {
      int rr = wave*16 + (lane>>4)*4;
      int cc = lane & 15;
#pragma unroll
      for (int t=0;t<8;t++)
#pragma unroll
        for (int r=0;r<4;r++)
          Cls[(rr + r)*CPAD + t*16 + cc] = acc[t][r];
    }
    __syncthreads();
    {
      int r = tid >> 2, cb = (tid & 3) * 32;
      int gr = row0 + r;
      if (gr < M){
#pragma unroll
        for (int j=0;j<8;j++){
          int c = cb + j*4;
          float4 o = *(float4*)&Cls[r*CPAD + c];
          if (ph == 0 && EPIQ == EPI_SCALE_CONST){
            o.x*=svec[c+0]; o.y*=svec[c+1]; o.z*=svec[c+2]; o.w*=svec[c+3];
          }
          if (FP8KV){
            int hh = c >> 4, c4 = c & 15;
            if (ph == 0){
              us4 ob; ob.x=f2b(o.x); ob.y=f2b(o.y); ob.z=f2b(o.z); ob.w=f2b(o.w);
              *(us4*)((unsigned short*)Cs[0] + ((size_t)hh*M + gr)*16 + c4) = ob;
            } else {
              unsigned char* Cb = (unsigned char*)Cs[1];
              uchar4 ob;
              ob.x=f2f8(o.x*8.f); ob.y=f2f8(o.y*8.f);
              ob.z=f2f8(o.z*8.f); ob.w=f2f8(o.w*8.f);
              *(uchar4*)(Cb + ((size_t)hh*M + gr)*32 + (ph==2?16:0) + c4) = ob;
            }
          } else {
            us4 ob; ob.x=f2b(o.x); ob.y=f2b(o.y); ob.z=f2b(o.z); ob.w=f2b(o.w);
            *(us4*)((unsigned short*)Cs[ph] + (size_t)gr*sts[ph] + c) = ob;
          }
        }
      }
    }
    __syncthreads();
  }
}

// Merged big+meta QKV in one dispatch: blocks [0,gN) big graph (bf16 in,
// head-major qh/kvh out); blocks [gN, gN+gm) meta graph (f32 in, node-major).
__global__ __launch_bounds__(256) void gemm_qkv2(
    const unsigned short* __restrict__ featB, const float* __restrict__ featM,
    const unsigned short* __restrict__ wqb, const unsigned short* __restrict__ wkb,
    const unsigned short* __restrict__ wvb,
    const unsigned short* __restrict__ wqm, const unsigned short* __restrict__ wkm,
    const unsigned short* __restrict__ wvm,
    unsigned short* __restrict__ qh, unsigned char* __restrict__ kvh,
    unsigned short* __restrict__ qM, unsigned short* __restrict__ kfM,
    unsigned short* __restrict__ vM,
    int Nbig, int Nmeta, int gN, const float* __restrict__ svec)
{
  __shared__ __align__(16) unsigned short Asb[64*128];
  __shared__ __align__(16) unsigned short Btb[16896];
  if (blockIdx.x < gN){
    qkv_body<EPI_STORE,true,true>(Asb, Btb, blockIdx.x, featB,
        wqb, wkb, wvb, qh, kvh, 0, nullptr, 0, Nbig, svec);
  } else {
    qkv_body<EPI_SCALE_CONST,false,false>(Asb, Btb, blockIdx.x - gN, featM,
        wqm, wkm, wvm, qM, kfM, DD, vM, DD, Nmeta, svec);
  }
}

// Static param-name graph -> base params.  (k_detect fused in.)
__global__ __launch_bounds__(256) void k_static(
    const void* __restrict__ emb, const int* __restrict__ svals,
    const int* __restrict__ ssrc, const int* __restrict__ sdst,
    const void* __restrict__ u, const void* __restrict__ W2,
    const void* __restrict__ W1, float* __restrict__ base, int nsrc,
    int* __restrict__ dflag)
{
  __shared__ float sagg[15][128];
  __shared__ float ssc[15][16];
  __shared__ float sww[15][16];
  __shared__ int swf;
  const int t = threadIdx.x;
  if (t < 64){
    float m = 0.f;
    for (int i=t; i<128; i+=64){
      float x = fabsf(b2f(((const unsigned short*)emb)[i]));
      if (x < 1e30f) m = fmaxf(m, x);
    }
#pragma unroll
    for (int s=1;s<64;s<<=1) m = fmaxf(m, __shfl_xor(m, s, 64));
    if (t==0){ int f = (m > 1e4f) ? 1 : 0; *dflag = f; swf = f; }
  }
  for (int i=t;i<15*128;i+=256) ((float*)sagg)[i]=0.f;
  __syncthreads();
  const bool wf32 = (swf != 0);
  if (t < 128){
    for (int i=0;i<nsrc;i++){
      int row = sdst[i]; int vr = svals[ssrc[i]];
      sagg[row][t] += gld(emb, (size_t)vr*DD + t, wf32);
    }
  }
  __syncthreads();
  if (t < 240){
    int n = t>>4, l = t&15;
    float a=0.f;
    for (int d=0;d<128;d++) a += sagg[n][d]*gld(u, l*128+d, wf32);
    ssc[n][l] = a * 0.08838834764831845f;
  }
  __syncthreads();
  if (t < 15){
    float mx=-1e30f;
    for (int l=0;l<16;l++) mx = fmaxf(mx, ssc[t][l]);
    float s=0.f;
    for (int l=0;l<16;l++){ float e=__expf(ssc[t][l]-mx); sww[t][l]=e; s+=e; }
    float inv = 1.f/s;
    for (int l=0;l<16;l++) sww[t][l]*=inv;
  }
  __syncthreads();
  if (t < 8){
    float a=0.f,b=0.f,c=0.f;
    for (int l=0;l<16;l++){
      float wv = gld(W1, l*8+t, wf32);
      a += sww[0][l]*wv; b += sww[3][l]*wv; c += sww[9][l]*wv;
    }
    base[t]=a; base[8+t]=b; base[16+t]=c;
  }
  if (t < 128){
    float a=0.f,b=0.f;
    for (int l=0;l<16;l++){
      float wv = gld(W2, l*128+t, wf32);
      a += sww[6][l]*wv; b += sww[12][l]*wv;
    }
    base[24+t]=a; base[152+t]=b;
  }
}

// Merged gather: big graph rows -> bf16 feat; meta rows -> f32 meta_feat.
__global__ __launch_bounds__(256) void gather_rows2(
    const void* __restrict__ emb,
    const int* __restrict__ valsB, unsigned short* __restrict__ featB, int nB,
    const int* __restrict__ valsM, float* __restrict__ featM, int nM,
    const int* __restrict__ dflag)
{
  const bool wf32 = (*dflag) != 0;
  int i = blockIdx.x*256 + threadIdx.x;
  bool big = (i < nB*16);
  int i2 = big ? i : (i - nB*16);
  if (!big && i2 >= nM*16) return;
  int r = i2>>4, c = (i2&15)*8;
  int vr = big ? valsB[r] : valsM[r];
  float vb[8];
  if (wf32){
    float4 f0 = *(const float4*)((const float*)emb + (size_t)vr*DD + c);
    float4 f1 = *(const float4*)((const float*)emb + (size_t)vr*DD + c + 4);
    vb[0]=f0.x; vb[1]=f0.y; vb[2]=f0.z; vb[3]=f0.w;
    vb[4]=f1.x; vb[5]=f1.y; vb[6]=f1.z; vb[7]=f1.w;
  } else {
    uint4 raw = *(const uint4*)((const unsigned short*)emb + (size_t)vr*DD + c);
    const unsigned short* hw = (const unsigned short*)&raw;
#pragma unroll
    for (int j=0;j<8;j++) vb[j] = b2f(hw[j]);
  }
  if (big){
    unsigned short* d = featB + (size_t)r*DD + c;
    us4 o0, o1;
    o0.x=f2b(vb[0]); o0.y=f2b(vb[1]); o0.z=f2b(vb[2]); o0.w=f2b(vb[3]);
    o1.x=f2b(vb[4]); o1.y=f2b(vb[5]); o1.z=f2b(vb[6]); o1.w=f2b(vb[7]);
    *(us4*)d = o0; *(us4*)(d+4) = o1;
  } else {
    float* d = featM + (size_t)r*DD + c;
    *(float4*)d     = make_float4(vb[0],vb[1],vb[2],vb[3]);
    *(float4*)(d+4) = make_float4(vb[4],vb[5],vb[6],vb[7]);
  }
}

__global__ __launch_bounds__(256) void zeroi(int* __restrict__ p, int n){
  int i = blockIdx.x*256 + threadIdx.x;
  if (i < n) p[i] = 0;
}

// ---------------- merged CSR build (big + meta graphs) ----------------
__global__ __launch_bounds__(256) void k_hist2(
    const int* __restrict__ dstB, const int* __restrict__ dstM,
    int* __restrict__ degB, int* __restrict__ degM, int E, int ME, int nbE){
  int b = blockIdx.x, t = threadIdx.x;
  if (b < nbE){ int i = b*256+t; if (i < E) atomicAdd(&degB[dstB[i]], 1); }
  else { int i = (b-nbE)*256+t; if (i < ME) atomicAdd(&degM[dstM[i]], 1); }
}

__global__ __launch_bounds__(256) void k_scan1b(
    const int* __restrict__ degB, int* __restrict__ rpB, int* __restrict__ bsB,
    int nB, int nbB,
    const int* __restrict__ degM, int* __restrict__ rpM, int* __restrict__ bsM,
    int nM){
  __shared__ int ls[256];
  int blk = blockIdx.x, t = threadIdx.x;
  const int* deg; int* rowptr; int* bsum; int n; int b;
  if (blk < nbB){ deg=degB; rowptr=rpB; bsum=bsB; n=nB; b=blk; }
  else          { deg=degM; rowptr=rpM; bsum=bsM; n=nM; b=blk-nbB; }
  int base = b*1024 + t*4;
  int v0 = (base+0<n)?deg[base+0]:0;
  int v1 = (base+1<n)?deg[base+1]:0;
  int v2 = (base+2<n)?deg[base+2]:0;
  int v3 = (base+3<n)?deg[base+3]:0;
  int tsum = v0+v1+v2+v3;
  ls[t] = tsum; __syncthreads();
  for (int o=1;o<256;o<<=1){
    int x = (t>=o) ? ls[t-o] : 0;
    __syncthreads();
    ls[t] += x;
    __syncthreads();
  }
  int excl = ls[t]-tsum;
  if (t==255) bsum[b] = ls[255];
  if (base+0<n) rowptr[base+0]=excl;
  if (base+1<n) rowptr[base+1]=excl+v0;
  if (base+2<n) rowptr[base+2]=excl+v0+v1;
  if (base+3<n) rowptr[base+3]=excl+v0+v1+v2;
}

// scan3 with in-block prefix of block sums (scan2 merged in).
__global__ __launch_bounds__(256) void k_scan3b(
    int* __restrict__ rpB, const int* __restrict__ bsB, int* __restrict__ curB,
    int nB, int nb3B, int nbsB,
    int* __restrict__ rpM, const int* __restrict__ bsM, int* __restrict__ curM,
    int nM, int nbsM){
  __shared__ int spre;
  int blk = blockIdx.x, t = threadIdx.x;
  if (blk < nb3B){
    if (t == 0){
      int chunk = blk >> 2;
      int pre = 0;
      for (int j=0;j<chunk;j++) pre += bsB[j];
      spre = pre;
      if (blk == 0){
        int tot = 0;
        for (int j=0;j<nbsB;j++) tot += bsB[j];
        rpB[nB] = tot;
      }
    }
    __syncthreads();
    int i = blk*256 + t;
    if (i < nB){ int r = rpB[i] + spre; rpB[i] = r; curB[i] = r; }
  } else {
    int b2 = blk - nb3B;
    if (t == 0){
      int chunk = b2 >> 2;
      int pre = 0;
      for (int j=0;j<chunk;j++) pre += bsM[j];
      spre = pre;
      if (b2 == 0){
        int tot = 0;
        for (int j=0;j<nbsM;j++) tot += bsM[j];
        rpM[nM] = tot;
      }
    }
    __syncthreads();
    int i = b2*256 + t;
    if (i < nM){ int r = rpM[i] + spre; rpM[i] = r; curM[i] = r; }
  }
}

// scatter. Big graph: pack (src | meid<<17) into one int.
// Extra final block: exclusive scan of dbins -> dcur (degree-sort cursors).
__global__ __launch_bounds__(256) void k_scatter2(
    const int* __restrict__ dstB, const int* __restrict__ srcB,
    const int* __restrict__ auxB, int* __restrict__ curB,
    int* __restrict__ epackB, int E, int nbE,
    const int* __restrict__ dstM, const int* __restrict__ srcM,
    int* __restrict__ curM, int* __restrict__ esrcM, int* __restrict__ eauxM,
    int ME, int nbME,
    const int* __restrict__ dbins, int* __restrict__ dcur){
  int blk = blockIdx.x, t = threadIdx.x;
  if (blk < nbE){
    int e = blk*256 + t;
    if (e < E){
      int p = atomicAdd(&curB[dstB[e]], 1);
      epackB[p] = srcB[e] | (auxB[e] << 17);
    }
  } else if (blk < nbE + nbME){
    int e = (blk-nbE)*256 + t;
    if (e < ME){
      int p = atomicAdd(&curM[dstM[e]], 1);
      esrcM[p] = srcM[e];
      eauxM[p] = e;
    }
  } else {
    if (t == 0){
      int run = 0;
      for (int j=0;j<64;j++){ dcur[j] = run; run += dbins[j]; }
    }
  }
}

// degree histogram: per-block LDS hist, then <=64 global atomics per block.
__global__ __launch_bounds__(256) void k_dhist(
    const int* __restrict__ deg, int* __restrict__ dbins, int N){
  __shared__ int lh[64];
  int t = threadIdx.x;
  if (t < 64) lh[t] = 0;
  __syncthreads();
  int i = blockIdx.x*256 + t;
  if (i < N){
    int dg = deg[i]; if (dg > 63) dg = 63;
    atomicAdd(&lh[dg], 1);
  }
  __syncthreads();
  if (t < 64 && lh[t]) atomicAdd(&dbins[t], lh[t]);
}

// counting-sort scatter: LDS-rank within block, one chunk-reservation atomic
// per (block,bin), conflict-free global writes.
__global__ __launch_bounds__(256) void k_dsort(
    const int* __restrict__ deg, int* __restrict__ dcur,
    int* __restrict__ sortN, int N){
  __shared__ int lh[64];
  __shared__ int gbase[64];
  int t = threadIdx.x;
  if (t < 64) lh[t] = 0;
  __syncthreads();
  int i = blockIdx.x*256 + t;
  int dg = 0, rank = 0;
  bool act = (i < N);
  if (act){
    dg = deg[i]; if (dg > 63) dg = 63;
    rank = atomicAdd(&lh[dg], 1);
  }
  __syncthreads();
  if (t < 64 && lh[t]) gbase[t] = atomicAdd(&dcur[t], lh[t]);
  __syncthreads();
  if (act) sortN[gbase[dg] + rank] = i;
}

// ---------------- meta-graph edges: CSR, atomic-free, writes mef ----------------
// agg written PRE-NORMALIZED (softmax denominator folded in here).
__global__ __launch_bounds__(256) void edge_meta_csr(
    const int* __restrict__ rowptr, const int* __restrict__ esrc,
    const int* __restrict__ eorig,
    const unsigned short* __restrict__ qm, const unsigned short* __restrict__ kfm,
    const unsigned short* __restrict__ vm,
    const float* __restrict__ base, unsigned short* __restrict__ mef,
    float* __restrict__ agg, int NM)
{
  int d = blockIdx.x*4 + (threadIdx.x>>6);
  if (d >= NM) return;
  int lane = threadIdx.x & 63;
  const float* be2 = base+152; const float* be1 = base+16; const float* bn1 = base+8;
  size_t dq = (size_t)d*DD;
  float q0 = b2f(qm[dq+lane]), q1 = b2f(qm[dq+64+lane]);
  float w0 = be2[lane], w1 = be2[64+lane];
  int h0 = lane>>4, h1 = h0+4;
  float bias0 = be1[h0] + bn1[h0];
  float bias1 = be1[h1] + bn1[h1];
  float z0=0.f, z1=0.f, a0=0.f, a1=0.f;
  int i0 = rowptr[d], i1 = rowptr[d+1];
  for (int i=i0; i<i1; i++){
    int s = esrc[i], e = eorig[i];
    size_t so=(size_t)s*DD, eo=(size_t)e*DD;
    float ke0 = b2f(kfm[so+lane])    * w0;
    float ke1 = b2f(kfm[so+64+lane]) * w1;
    mef[eo+lane]=f2b(ke0); mef[eo+64+lane]=f2b(ke1);
    float p0 = q0*ke0, p1 = q1*ke1;
#pragma unroll
    for (int m=1;m<16;m<<=1){ p0 += __shfl_xor(p0,m,64); p1 += __shfl_xor(p1,m,64); }
    float e0 = __expf(p0*0.25f + bias0);
    float e1 = __expf(p1*0.25f + bias1);
    z0 += e0; z1 += e1;
    a0 += e0*b2f(vm[so+lane]);
    a1 += e1*b2f(vm[so+64+lane]);
  }
  float inv0 = 1.f/(z0 + 1e-9f);
  float inv1 = 1.f/(z1 + 1e-9f);
  agg[dq+lane]    = a0*inv0;
  agg[dq+64+lane] = a1*inv1;
}

// Fused meta-learner over [meta_out (Ma rows, f32) | mef (bf16)].
// 4 rows per block; u/W2/W1 columns cached in registers across rows.
// Outputs are HEAD-MAJOR: qsch [8][MN][16], w2meh [8][ME][16] (bf16).
__global__ __launch_bounds__(128) void learner2(
    const float* __restrict__ Xa, const unsigned short* __restrict__ Xb,
    int Ma, int Mtot,
    const void* __restrict__ u, const void* __restrict__ W2,
    const void* __restrict__ W1,
    unsigned short* __restrict__ qsch, float* __restrict__ p1a,
    unsigned short* __restrict__ w2meh, unsigned short* __restrict__ p1b,
    const float* __restrict__ base, const int* __restrict__ dflag)
{
  __shared__ float sX[128];
  __shared__ float st[16];
  __shared__ float sw[16];
  const bool wf32 = (*dflag) != 0;
  const int MEc = Mtot - Ma;
  const int t = threadIdx.x;
  const int l = t>>3, j = t&7;
  const int th = t >> 4, tc = t & 15;     // head, channel for head-major writes
  float uc[16], w2c[16], w1c[16];
#pragma unroll
  for (int m=0;m<16;m++) uc[m] = gld(u, (size_t)l*128 + j*16 + m, wf32);
#pragma unroll
  for (int i=0;i<16;i++) w2c[i] = gld(W2, (size_t)i*128 + t, wf32);
  if (t < 8){
#pragma unroll
    for (int i=0;i<16;i++) w1c[i] = gld(W1, (size_t)i*8 + t, wf32);
  }
  for (int rr=0; rr<4; rr++){
    int row = blockIdx.x*4 + rr;
    if (row >= Mtot) break;
    const bool isB = (row >= Ma);
    const int m = isB ? (row - Ma) : row;
    if (isB) sX[t] = b2f(Xb[(size_t)m*DD + t]);
    else     sX[t] = Xa[(size_t)m*DD + t];
    __syncthreads();
    float part = 0.f;
#pragma unroll
    for (int mm=0;mm<16;mm++) part += sX[j*16+mm]*uc[mm];
    part += __shfl_xor(part,1,64); part += __shfl_xor(part,2,64); part += __shfl_xor(part,4,64);
    if (j==0) st[l] = part * 0.08838834764831845f;
    __syncthreads();
    float mx=-1e30f;
    for (int i=0;i<16;i++) mx = fmaxf(mx, st[i]);
    float ssum=0.f;
    for (int i=0;i<16;i++) ssum += __expf(st[i]-mx);
    float inv = 1.f/ssum;
    if (t<16) sw[t] = __expf(st[t]-mx)*inv;
    __syncthreads();
    float a=0.f;
#pragma unroll
    for (int i=0;i<16;i++) a += sw[i]*w2c[i];
    if (isB) w2meh[((size_t)th*MEc + m)*16 + tc] = f2b(base[152+t] + a);
    else     qsch [((size_t)th*Ma  + m)*16 + tc] = f2b(base[24+t] + a);
    if (t<8){
      float bb=0.f;
#pragma unroll
      for (int i=0;i<16;i++) bb += sw[i]*w1c[i];
      if (isB) p1b[(size_t)m*HH+t] = f2b(bb);
      else     p1a[(size_t)m*HH+t] = bb;
    }
    __syncthreads();
  }
}

// ---------------- big-graph: fused scores+agg, XCD-AFFINE head sharding -----
// Work item = (node, head); one LANE-PAIR per item (8 channels/lane).
// head = blockIdx%8 -> with round-robin block->XCD dispatch, head h's slices
// (kvh/qh/w2meh/qsch, each <=3.2MB) are resident in XCD h's private L2, so the
// E random kv gathers become L2 hits instead of ~205MB of cross-L2 traffic.
// Degree-sorted item order keeps the wave's 32 pairs at equal trip counts.
// agg PRE-NORMALIZED (0.125 fp8 v-descale folded into 1/z).
__global__ __launch_bounds__(256) void edge_fused(
    const int* __restrict__ rowptr, const int* __restrict__ epack,
    const int* __restrict__ sortN, const int* __restrict__ mnid,
    const unsigned short* __restrict__ qh, const unsigned char* __restrict__ kvh,
    const unsigned short* __restrict__ w2meh, const unsigned short* __restrict__ p1me,
    const float* __restrict__ p1mn, const unsigned short* __restrict__ qsch,
    const float* __restrict__ base,
    unsigned short* __restrict__ aggb, int N, int MEc, int MNc)
{
  const int tid = threadIdx.x;
  const int lane = tid & 63;
  const int h = blockIdx.x & 7;             // head == XCD (round-robin)
  const int chunk = blockIdx.x >> 3;
  const int item = chunk*128 + (tid>>6)*32 + (lane>>1);
  if (item >= N) return;
  const int p = lane & 1;
  const int d = sortN[item];
  const int i0 = rowptr[d], i1 = rowptr[d+1];
  const int mn = mnid[d];
  const float bias = base[16+h] + base[8+h] + p1mn[(size_t)mn*HH + h];

  float qv[8];
  {
    uint4 qraw = *(const uint4*)(qh  + ((size_t)h*N   + d )*16 + p*8);
    uint4 scr  = *(const uint4*)(qsch+ ((size_t)h*MNc + mn)*16 + p*8);
    const unsigned short* qw = (const unsigned short*)&qraw;
    const unsigned short* sc = (const unsigned short*)&scr;
#pragma unroll
    for (int j=0;j<8;j++) qv[j] = b2f(qw[j]) * b2f(sc[j]) * 0.03125f; // 0.25/8
  }

  float zh = 0.f;
  float a[8];
#pragma unroll
  for (int j=0;j<8;j++) a[j] = 0.f;

  int i = i0;
  for (; i + 1 < i1; i += 2){
    unsigned int v0p = (unsigned int)epack[i];
    unsigned int v1p = (unsigned int)epack[i+1];
    int s0 = v0p & 0x1FFFF, me0 = v0p >> 17;
    int s1 = v1p & 0x1FFFF, me1 = v1p >> 17;
    const unsigned char* kv0 = kvh + ((size_t)h*N + s0)*32 + p*8;
    const unsigned char* kv1 = kvh + ((size_t)h*N + s1)*32 + p*8;
    uint2 kraw0 = *(const uint2*)kv0;
    uint2 vraw0 = *(const uint2*)(kv0 + 16);
    uint4 wraw0 = *(const uint4*)(w2meh + ((size_t)h*MEc + me0)*16 + p*8);
    float pm0 = b2f(p1me[(size_t)me0*HH + h]);
    uint2 kraw1 = *(const uint2*)kv1;
    uint2 vraw1 = *(const uint2*)(kv1 + 16);
    uint4 wraw1 = *(const uint4*)(w2meh + ((size_t)h*MEc + me1)*16 + p*8);
    float pm1 = b2f(p1me[(size_t)me1*HH + h]);
    float k0f[8], v0f[8], k1f[8], v1f[8];
    cvt4(kraw0.x, k0f); cvt4(kraw0.y, k0f+4);
    cvt4(vraw0.x, v0f); cvt4(vraw0.y, v0f+4);
    cvt4(kraw1.x, k1f); cvt4(kraw1.y, k1f+4);
    cvt4(vraw1.x, v1f); cvt4(vraw1.y, v1f+4);
    const unsigned short* wh0 = (const unsigned short*)&wraw0;
    const unsigned short* wh1 = (const unsigned short*)&wraw1;
    float pA = 0.f, pB = 0.f;
#pragma unroll
    for (int j=0;j<8;j++){
      pA += qv[j]*(k0f[j]*b2f(wh0[j]));
      pB += qv[j]*(k1f[j]*b2f(wh1[j]));
    }
    pA += __shfl_xor(pA, 1, 64);
    pB += __shfl_xor(pB, 1, 64);
    float ex0 = __expf(pA + bias + pm0);
    float ex1 = __expf(pB + bias + pm1);
    zh += ex0 + ex1;
#pragma unroll
    for (int j=0;j<8;j++) a[j] += ex0*v0f[j] + ex1*v1f[j];
  }
  if (i < i1){
    unsigned int vp = (unsigned int)epack[i];
    int s = vp & 0x1FFFF, me = vp >> 17;
    const unsigned char* kv = kvh + ((size_t)h*N + s)*32 + p*8;
    uint2 kraw = *(const uint2*)kv;
    uint2 vraw = *(const uint2*)(kv + 16);
    uint4 wraw = *(const uint4*)(w2meh + ((size_t)h*MEc + me)*16 + p*8);
    float pm = b2f(p1me[(size_t)me*HH + h]);
    float kf[8], vf[8];
    cvt4(kraw.x, kf); cvt4(kraw.y, kf+4);
    cvt4(vraw.x, vf); cvt4(vraw.y, vf+4);
    const unsigned short* wh = (const unsigned short*)&wraw;
    float pfull = 0.f;
#pragma unroll
    for (int j=0;j<8;j++) pfull += qv[j]*(kf[j]*b2f(wh[j]));
    pfull += __shfl_xor(pfull, 1, 64);
    float ex = __expf(pfull + bias + pm);
    zh += ex;
#pragma unroll
    for (int j=0;j<8;j++) a[j] += ex*vf[j];
  }

  float inv = 0.125f / (zh + 1e-9f);   // fp8 v-descale folded into 1/z
  us8 o;
#pragma unroll
  for (int j=0;j<8;j++) o.s[j] = f2b(a[j]*inv);
  *(us8*)(aggb + (size_t)d*DD + h*16 + p*8) = o;
}

// One 16-lane group per target; vectorized feat row read + shuffle reduce.
__global__ __launch_bounds__(256) void readout(
    const int* __restrict__ tgt, const int* __restrict__ mnid,
    const unsigned short* __restrict__ featb, const float* __restrict__ p1mn,
    const float* __restrict__ base, float* __restrict__ acc,
    void* __restrict__ out, int last, float invNB, int BT,
    const int* __restrict__ dflag)
{
  int t = blockIdx.x*256 + threadIdx.x;
  int ti = t >> 4, l16 = t & 15;
  if (ti >= BT) return;
  int idx = tgt[ti]; int mn = mnid[idx];
  int h = l16 >> 1;
  float tw = base[h] + p1mn[(size_t)mn*HH + h];
  uint4 raw = *(const uint4*)(featb + (size_t)idx*DD + l16*8);
  const unsigned short* hw = (const unsigned short*)&raw;
  float s = 0.f;
#pragma unroll
  for (int j=0;j<8;j++) s += b2f(hw[j]);
  float part = tw * s;
  part += __shfl_xor(part, 1, 64);
  part += __shfl_xor(part, 2, 64);
  part += __shfl_xor(part, 4, 64);
  part += __shfl_xor(part, 8, 64);
  if (l16 == 0){
    if (!last) acc[ti] = part;
    else {
      float r = (acc[ti] + part) * invNB;
      if ((*dflag) != 0) ((float*)out)[ti] = r;
      else ((__hip_bfloat16*)out)[ti] = __float2bfloat16(r);
    }
  }
}

extern "C" void kernel_launch(void* const* d_in, const int* in_sizes, int n_in,
                              void* d_out, int out_size, void* d_ws, size_t ws_size,
                              hipStream_t stream) {
  const void* emb   = d_in[0];
  const void* u     = d_in[1];
  const void* W2lat = d_in[2];
  const void* W1lat = d_in[3];
  WPtrs wptrs;
  for (int i=0;i<8;i++) wptrs.p[i] = d_in[4+i];
  const int* node_vals      = (const int*)d_in[12];
  const int* meta_node_vals = (const int*)d_in[13];
  const int* src            = (const int*)d_in[14];
  const int* dst            = (const int*)d_in[15];
  const int* meta_src       = (const int*)d_in[16];
  const int* meta_dst       = (const int*)d_in[17];
  const int* meta_node_id   = (const int*)d_in[18];
  const int* meta_edge_id   = (const int*)d_in[19];
  const int* target_idx     = (const int*)d_in[20];
  const int* static_vals    = (const int*)d_in[21];
  const int* static_src     = (const int*)d_in[22];
  const int* static_dst     = (const int*)d_in[23];

  const int N  = in_sizes[12];
  const int MN = in_sizes[13];
  const int E  = in_sizes[14];
  const int ME = in_sizes[16];
  const int BT = in_sizes[20];
  const int NSRC = in_sizes[22];
  const int NB = in_sizes[8] / (DD*DD);

  float* ws = (float*)d_ws;
  size_t off = 0;
  // keep every allocation 16B-aligned (global_load_lds sources need it)
  auto allocf = [&](size_t n){ float* p = ws + off; off += (n + 3) & ~(size_t)3; return p; };
  auto allocb = [&](size_t n){ unsigned short* p = (unsigned short*)(ws + off); off += (((n+1)/2) + 3) & ~(size_t)3; return p; };
  auto alloci = [&](size_t n){ int* p = (int*)(ws + off); off += (n + 3) & ~(size_t)3; return p; };
  int*            dflag = (int*)ws; off += 4;
  unsigned short* feat  = allocb((size_t)N*DD);
  unsigned short* qh    = allocb((size_t)N*DD);                 // [8][N][16] bf16
  unsigned char*  kvh   = (unsigned char*)allocf((size_t)N*64); // [8][N][32] fp8
  unsigned short* aggb  = allocb((size_t)N*DD);
  float*          meta_feat= allocf((size_t)MN*DD);
  float*          agg_m = allocf((size_t)MN*DD);
  unsigned short* q_m   = allocb((size_t)MN*DD);
  unsigned short* kf_m  = allocb((size_t)MN*DD);
  unsigned short* v_m   = allocb((size_t)MN*DD);
  float*          meta_out = allocf((size_t)MN*DD);
  unsigned short* mef   = allocb((size_t)ME*DD);
  unsigned short* qsch  = allocb((size_t)MN*DD);   // [8][MN][16] bf16
  float*          p1mn  = allocf((size_t)MN*HH);
  unsigned short* w2meh = allocb((size_t)ME*DD);   // [8][ME][16] bf16
  unsigned short* p1me  = allocb((size_t)ME*HH);
  float*          base  = allocf(280);
  float*          acc   = allocf((size_t)BT);
  unsigned short* wstage= allocb((size_t)8*NB*DD*DD);
  int*            rowptr= alloci((size_t)N+1);
  int*            cursor= alloci((size_t)N);
  int*            epack = alloci((size_t)E);
  int*            rowptr_m= alloci((size_t)MN+1);
  int*            cursor_m= alloci((size_t)MN);
  int*            esrc_m  = alloci((size_t)ME);
  int*            eorig_m = alloci((size_t)ME);
  int*            dbins   = alloci(64);            // contiguous with degAll
  int*            degAll  = alloci((size_t)(N+MN));
  int*            deg     = degAll;
  int*            deg_m   = degAll + N;
  int*            dcur    = alloci(64);
  int*            sortN   = alloci((size_t)N);
  const int nb_scan   = (N + 1023)/1024;
  const int nb_scan_m = (MN + 1023)/1024;
  int*            bsum   = alloci((size_t)nb_scan);
  int*            bsum_m = alloci((size_t)nb_scan_m);
  (void)ws_size; (void)n_in; (void)out_size;

  const float* base_n2 = base + 24;

  k_static<<<1,256,0,stream>>>(emb, static_vals, static_src, static_dst,
                               u, W2lat, W1lat, base, NSRC, dflag);
  gather_rows2<<<((N+MN)*16+255)/256,256,0,stream>>>(emb, node_vals, feat, N,
      meta_node_vals, meta_feat, MN, dflag);

  const int nbE  = (E+255)/256, nbME = (ME+255)/256;
  const int nb3B = (N+255)/256, nb3M = (MN+255)/256;
  zeroi<<<(64+N+MN+255)/256,256,0,stream>>>(dbins, 64+N+MN);  // dbins+degAll contiguous
  k_hist2<<<nbE+nbME,256,0,stream>>>(dst, meta_dst, deg, deg_m, E, ME, nbE);
  k_dhist<<<(N+255)/256,256,0,stream>>>(deg, dbins, N);
  k_scan1b<<<nb_scan+nb_scan_m,256,0,stream>>>(deg, rowptr, bsum, N, nb_scan,
      deg_m, rowptr_m, bsum_m, MN);
  k_scan3b<<<nb3B+nb3M,256,0,stream>>>(rowptr, bsum, cursor, N, nb3B, nb_scan,
      rowptr_m, bsum_m, cursor_m, MN, nb_scan_m);
  k_scatter2<<<nbE+nbME+1,256,0,stream>>>(dst, src, meta_edge_id, cursor,
      epack, E, nbE, meta_dst, meta_src, cursor_m, esrc_m, eorig_m, ME, nbME,
      dbins, dcur);
  k_dsort<<<(N+255)/256,256,0,stream>>>(deg, dcur, sortN, N);

  w_repack16<<<8*NB*64,256,0,stream>>>(wptrs, wstage, NB, dflag);

  const int gm = (MN+63)/64;
  const int gN = (N+63)/64;
  const int gEF = 8 * ((N + 127)/128);
  const float invNB = 1.0f/(float)NB;

  for (int b=0;b<NB;b++){
    const unsigned short* wq_m = wstage + (size_t)(0*NB+b)*DD*DD;
    const unsigned short* wk_m = wstage + (size_t)(1*NB+b)*DD*DD;
    const unsigned short* wv_m = wstage + (size_t)(2*NB+b)*DD*DD;
    const unsigned short* wo_m = wstage + (size_t)(3*NB+b)*DD*DD;
    const unsigned short* wqb  = wstage + (size_t)(4*NB+b)*DD*DD;
    const unsigned short* wkb  = wstage + (size_t)(5*NB+b)*DD*DD;
    const unsigned short* wvb  = wstage + (size_t)(6*NB+b)*DD*DD;
    const unsigned short* wob  = wstage + (size_t)(7*NB+b)*DD*DD;

    // ---- merged big+meta QKV (big outputs head-major qh/kvh) ----
    gemm_qkv2<<<gN+gm,256,0,stream>>>(feat, meta_feat,
        wqb, wkb, wvb, wq_m, wk_m, wv_m,
        qh, kvh, q_m, kf_m, v_m, N, MN, gN, base_n2);

    // ---- meta conv (CSR, atomic-free) ----
    edge_meta_csr<<<(MN+3)/4,256,0,stream>>>(rowptr_m, esrc_m, eorig_m,
        q_m, kf_m, v_m, base, mef, agg_m, MN);
    // meta Wo: meta_out = relu(agg_m@Wo) (f32, agg pre-normalized); meta_feat += relu
    gemm128m<EPI_RELU_RES2,false,false><<<gm,256,0,stream>>>(agg_m, wo_m,
        meta_out, MN, nullptr, meta_feat, meta_feat);
    // wide fused learners: MN rows (f32 meta_out) + ME rows (bf16 mef)
    learner2<<<(MN+ME+3)/4,128,0,stream>>>(meta_out, mef, MN, MN+ME,
        u, W2lat, W1lat, qsch, p1mn, w2meh, p1me, base, dflag);

    // ---- big conv (XCD-affine head shards, degree-balanced lane pairs) ----
    edge_fused<<<gEF,256,0,stream>>>(rowptr, epack, sortN,
        meta_node_id, qh, kvh, w2meh, p1me, p1mn, qsch, base, aggb, N, ME, MN);
    gemm128m<EPI_RELU_RES,true,true><<<gN,256,0,stream>>>(aggb, wob, feat, N,
        feat, nullptr, nullptr);

    // ---- readout ----
    readout<<<(BT*16+255)/256,256,0,stream>>>(target_idx, meta_node_id, feat, p1mn,
        base, acc, d_out, (b==NB-1) ? 1 : 0, invNB, BT, dflag);
  }
}

// Round 8
// 594.223 us; speedup vs baseline: 1.2958x; 1.2958x over previous
//
#include <hip/hip_runtime.h>
#include <hip/hip_bf16.h>
#include <hip/hip_fp8.h>

#define DD   128
#define HH   8

typedef short bf16x8 __attribute__((ext_vector_type(8)));
typedef float f32x4  __attribute__((ext_vector_type(4)));
typedef float f32x2  __attribute__((ext_vector_type(2)));

__device__ __forceinline__ float b2f(unsigned short v){
  union { unsigned int u; float f; } x; x.u = ((unsigned int)v) << 16; return x.f;
}
__device__ __forceinline__ unsigned short f2b(float f){
  __hip_bfloat16 h = __float2bfloat16(f);
  return *(unsigned short*)&h;
}
__device__ __forceinline__ unsigned char f2f8(float x){
  __hip_fp8_e4m3 h(x);
  return h.__x;
}
__device__ __forceinline__ float f82f(unsigned char b){
  __hip_fp8_e4m3 h; h.__x = b;
  return (float)h;
}
// 4 fp8 bytes (one u32) -> 4 floats; HW packed cvt when available.
__device__ __forceinline__ void cvt4(unsigned int w, float* o){
#if defined(__has_builtin)
# if __has_builtin(__builtin_amdgcn_cvt_pk_f32_fp8)
  f32x2 lo = __builtin_amdgcn_cvt_pk_f32_fp8((int)w, false);
  f32x2 hi = __builtin_amdgcn_cvt_pk_f32_fp8((int)w, true);
  o[0]=lo[0]; o[1]=lo[1]; o[2]=hi[0]; o[3]=hi[1];
  return;
# endif
#endif
  o[0]=f82f(w&0xff); o[1]=f82f((w>>8)&0xff);
  o[2]=f82f((w>>16)&0xff); o[3]=f82f((w>>24)&0xff);
}
struct __align__(8) us4 { unsigned short x,y,z,w; };
struct __align__(16) us8 { unsigned short s[8]; };

__device__ __forceinline__ float gld(const void* p, size_t i, bool f32){
  if (f32) return ((const float*)p)[i];
  return b2f(((const unsigned short*)p)[i]);
}

// async global->LDS, 16B per lane (wave-uniform LDS base + lane*16)
__device__ __forceinline__ void gll16(const void* g, void* l){
  __builtin_amdgcn_global_load_lds(
      (const __attribute__((address_space(1))) unsigned int*)g,
      (__attribute__((address_space(3))) unsigned int*)l, 16, 0, 0);
}

// ALL weight blocks (8 tensors x NB matrices) -> bf16 TRANSPOSED staging, one launch.
struct WPtrs { const void* p[8]; };
__global__ __launch_bounds__(256) void w_repack16(
    WPtrs W, unsigned short* __restrict__ stage, int NBt,
    const int* __restrict__ dflag)
{
  const bool wf32 = (*dflag) != 0;
  int idx = blockIdx.x >> 6;
  int ti = idx / NBt, bi = idx - ti*NBt;
  size_t bo = (size_t)bi*DD*DD;
  int i = (blockIdx.x & 63)*256 + threadIdx.x;
  int k = i >> 7, n = i & 127;
  float x;
  if (wf32) x = ((const float*)W.p[ti])[bo + i];
  else      x = b2f(((const unsigned short*)W.p[ti])[bo + i]);
  stage[(size_t)idx*DD*DD + n*DD + k] = f2b(x);
}

enum { EPI_STORE=0, EPI_SCALE_CONST=1, EPI_RELU=3,
       EPI_RELU_RES=4, EPI_RELU_RES2=5 };

#define CPAD 132

// C[M,128] = epi( A[M,128] @ B[128,128] ), B bf16 TRANSPOSED ([n][k]).
// EPI_RELU_RES : C = relu(x) + Rb(bf16)                  [big Wo, OUTB=1]
// EPI_RELU_RES2: Cv = relu(x) f32; C2 = relu(x)+Rf (f32) [meta Wo, OUTB=0]
template<int EPI, bool INB, bool OUTB>
__global__ __launch_bounds__(256) void gemm128m(
    const void* __restrict__ Av, const unsigned short* __restrict__ Bt,
    void* __restrict__ Cv, int M,
    const unsigned short* __restrict__ Rb,
    const float* __restrict__ Rf, float* __restrict__ C2)
{
  __shared__ __align__(16) unsigned short Asb[64*128];
  __shared__ __align__(16) unsigned short Btb[16896];  // B: 32KB / C: 64x132 f32
  const int tid = threadIdx.x;
  const int wave = tid >> 6, lane = tid & 63;
  const int row0 = blockIdx.x * 64;

  if (INB){
    const char* Ab = (const char*)Av;
    int n4 = lane >> 4, c = lane & 15;
#pragma unroll
    for (int op=0; op<4; op++){
      int rA = wave*16 + op*4;
      int n = rA + n4;
      int gr = row0 + n; if (gr >= M) gr = M - 1;
      gll16(Ab + (size_t)gr*256 + ((size_t)((c ^ (n & 7)) << 4)), &Asb[rA*128]);
    }
  } else {
    const float* Af = (const float*)Av;
    int r = tid >> 2, cb = (tid & 3) * 32, rx = (r & 7) << 3;
    int gr = row0 + r;
#pragma unroll
    for (int j=0;j<8;j++){
      int cc = cb + j*4;
      float4 val = make_float4(0.f,0.f,0.f,0.f);
      if (gr < M) val = *(const float4*)(Af + (size_t)gr*DD + cc);
      us4 o; o.x=f2b(val.x); o.y=f2b(val.y); o.z=f2b(val.z); o.w=f2b(val.w);
      *(us4*)&Asb[r*128 + (cc ^ rx)] = o;
    }
  }
  {
    int n4 = lane >> 4, c = lane & 15;
#pragma unroll
    for (int op=0; op<8; op++){
      int rB = wave*32 + op*4;
      int n = rB + n4;
      gll16((const char*)Bt + (size_t)n*256 + ((size_t)((c ^ (n & 7)) << 4)),
            &Btb[rB*128]);
    }
  }
  __syncthreads();

  f32x4 acc[8];
#pragma unroll
  for (int t=0;t<8;t++) acc[t] = (f32x4){0.f,0.f,0.f,0.f};
  const int am = (lane & 15), kq = (lane >> 4) * 8, axr = (am & 7) << 3;
#pragma unroll
  for (int k0=0;k0<128;k0+=32){
    int xo = (k0 + kq) ^ axr;
    bf16x8 a = *(bf16x8*)&Asb[(wave*16 + am)*128 + xo];
#pragma unroll
    for (int t=0;t<8;t++){
      bf16x8 b = *(bf16x8*)&Btb[(t*16 + am)*128 + xo];
      acc[t] = __builtin_amdgcn_mfma_f32_16x16x32_bf16(a, b, acc[t], 0,0,0);
    }
  }
  __syncthreads();
  float* Cls = (float*)Btb;
  {
    int rr = wave*16 + (lane>>4)*4;
    int cc = lane & 15;
#pragma unroll
    for (int t=0;t<8;t++)
#pragma unroll
      for (int r=0;r<4;r++)
        Cls[(rr + r)*CPAD + t*16 + cc] = acc[t][r];
  }
  __syncthreads();

  {
    int r = tid >> 2, cb = (tid & 3) * 32;
    int gr = row0 + r;
    if (gr < M){
#pragma unroll
      for (int j=0;j<8;j++){
        int c = cb + j*4;
        float4 o = *(float4*)&Cls[r*CPAD + c];
        if (EPI == EPI_RELU_RES){
          us4 rb = *(const us4*)(Rb + (size_t)gr*DD + c);
          o.x=fmaxf(o.x,0.f)+b2f(rb.x); o.y=fmaxf(o.y,0.f)+b2f(rb.y);
          o.z=fmaxf(o.z,0.f)+b2f(rb.z); o.w=fmaxf(o.w,0.f)+b2f(rb.w);
        } else if (EPI == EPI_RELU_RES2){
          o.x=fmaxf(o.x,0.f); o.y=fmaxf(o.y,0.f); o.z=fmaxf(o.z,0.f); o.w=fmaxf(o.w,0.f);
          float4 rf = *(const float4*)(Rf + (size_t)gr*DD + c);
          *(float4*)(C2 + (size_t)gr*DD + c) =
              make_float4(o.x+rf.x, o.y+rf.y, o.z+rf.z, o.w+rf.w);
        }
        if (OUTB){
          us4 ob; ob.x=f2b(o.x); ob.y=f2b(o.y); ob.z=f2b(o.z); ob.w=f2b(o.w);
          *(us4*)((unsigned short*)Cv + (size_t)gr*DD + c) = ob;
        } else {
          *(float4*)((float*)Cv + (size_t)gr*DD + c) = o;
        }
      }
    }
  }
}

// Fused QKV gemm body.
// KVONLY (big graph): 2 phases (K,V) -> fp8 x8 into node-major 256B kv rows
// (k at +0, v at +128).  Q is computed later (gemm_q1, after learner2).
// !KVONLY (meta): 3 phases q/k/v, node-major bf16, q scaled by svec.
template<int EPIQ, bool INB, bool KVONLY>
__device__ __forceinline__ void qkv_body(
    unsigned short* Asb, unsigned short* Btb, int blk,
    const void* __restrict__ Av,
    const unsigned short* __restrict__ Btq, const unsigned short* __restrict__ Btk,
    const unsigned short* __restrict__ Btv,
    void* __restrict__ Cq, void* __restrict__ Ck, int stK,
    void* __restrict__ Cvo, int stV, int M,
    const float* __restrict__ svec)
{
  const int tid = threadIdx.x;
  const int wave = tid >> 6, lane = tid & 63;
  const int row0 = blk * 64;

  if (INB){
    const char* Ab = (const char*)Av;
    int n4 = lane >> 4, c = lane & 15;
#pragma unroll
    for (int op=0; op<4; op++){
      int rA = wave*16 + op*4;
      int n = rA + n4;
      int gr = row0 + n; if (gr >= M) gr = M - 1;
      gll16(Ab + (size_t)gr*256 + ((size_t)((c ^ (n & 7)) << 4)), &Asb[rA*128]);
    }
  } else {
    const float* Af = (const float*)Av;
    int r = tid >> 2, cb = (tid & 3) * 32, rx = (r & 7) << 3;
    int gr = row0 + r;
#pragma unroll
    for (int j=0;j<8;j++){
      int cc = cb + j*4;
      float4 val = make_float4(0.f,0.f,0.f,0.f);
      if (gr < M) val = *(const float4*)(Af + (size_t)gr*DD + cc);
      us4 o; o.x=f2b(val.x); o.y=f2b(val.y); o.z=f2b(val.z); o.w=f2b(val.w);
      *(us4*)&Asb[r*128 + (cc ^ rx)] = o;
    }
  }

  const unsigned short* Bts[3] = {KVONLY ? Btk : Btq, KVONLY ? Btv : Btk, Btv};
  void* Cs[3] = {KVONLY ? Ck : Cq, Ck, Cvo};
  const int sts[3] = {DD, stK, stV};
  const int nph = KVONLY ? 2 : 3;
  const int am = (lane & 15), kq = (lane >> 4) * 8, axr = (am & 7) << 3;

  for (int ph=0; ph<nph; ph++){
    {
      const unsigned short* Bt = Bts[ph];
      int n4 = lane >> 4, c = lane & 15;
#pragma unroll
      for (int op=0; op<8; op++){
        int rB = wave*32 + op*4;
        int n = rB + n4;
        gll16((const char*)Bt + (size_t)n*256 + ((size_t)((c ^ (n & 7)) << 4)),
              &Btb[rB*128]);
      }
    }
    __syncthreads();
    f32x4 acc[8];
#pragma unroll
    for (int t=0;t<8;t++) acc[t] = (f32x4){0.f,0.f,0.f,0.f};
#pragma unroll
    for (int k0=0;k0<128;k0+=32){
      int xo = (k0 + kq) ^ axr;
      bf16x8 a = *(bf16x8*)&Asb[(wave*16 + am)*128 + xo];
#pragma unroll
      for (int t=0;t<8;t++){
        bf16x8 b = *(bf16x8*)&Btb[(t*16 + am)*128 + xo];
        acc[t] = __builtin_amdgcn_mfma_f32_16x16x32_bf16(a, b, acc[t], 0,0,0);
      }
    }
    __syncthreads();
    float* Cls = (float*)Btb;
    {
      int rr = wave*16 + (lane>>4)*4;
      int cc = lane & 15;
#pragma unroll
      for (int t=0;t<8;t++)
#pragma unroll
        for (int r=0;r<4;r++)
          Cls[(rr + r)*CPAD + t*16 + cc] = acc[t][r];
    }
    __syncthreads();
    {
      int r = tid >> 2, cb = (tid & 3) * 32;
      int gr = row0 + r;
      if (gr < M){
#pragma unroll
        for (int j=0;j<8;j++){
          int c = cb + j*4;
          float4 o = *(float4*)&Cls[r*CPAD + c];
          if (!KVONLY && ph == 0 && EPIQ == EPI_SCALE_CONST){
            o.x*=svec[c+0]; o.y*=svec[c+1]; o.z*=svec[c+2]; o.w*=svec[c+3];
          }
          if (KVONLY){
            unsigned char* Cb = (unsigned char*)Cs[0];
            uchar4 ob;
            ob.x=f2f8(o.x*8.f); ob.y=f2f8(o.y*8.f);
            ob.z=f2f8(o.z*8.f); ob.w=f2f8(o.w*8.f);
            *(uchar4*)(Cb + (size_t)gr*256 + ph*128 + c) = ob;
          } else {
            us4 ob; ob.x=f2b(o.x); ob.y=f2b(o.y); ob.z=f2b(o.z); ob.w=f2b(o.w);
            *(us4*)((unsigned short*)Cs[ph] + (size_t)gr*sts[ph] + c) = ob;
          }
        }
      }
    }
    __syncthreads();
  }
}

// Merged dispatch: blocks [0,gN) big-graph K+V (fp8 kv rows); blocks
// [gN,gN+gm) meta q/k/v.  Neither depends on the meta-learner chain.
__global__ __launch_bounds__(256) void gemm_qkv2(
    const unsigned short* __restrict__ featB, const float* __restrict__ featM,
    const unsigned short* __restrict__ wkb, const unsigned short* __restrict__ wvb,
    const unsigned short* __restrict__ wqm, const unsigned short* __restrict__ wkm,
    const unsigned short* __restrict__ wvm,
    unsigned char* __restrict__ kv8,
    unsigned short* __restrict__ qM, unsigned short* __restrict__ kfM,
    unsigned short* __restrict__ vM,
    int Nbig, int Nmeta, int gN, const float* __restrict__ svec)
{
  __shared__ __align__(16) unsigned short Asb[64*128];
  __shared__ __align__(16) unsigned short Btb[16896];
  if (blockIdx.x < gN){
    qkv_body<EPI_STORE,true,true>(Asb, Btb, blockIdx.x, featB,
        nullptr, wkb, wvb, nullptr, kv8, 0, nullptr, 0, Nbig, svec);
  } else {
    qkv_body<EPI_SCALE_CONST,false,false>(Asb, Btb, blockIdx.x - gN, featM,
        wqm, wkm, wvm, qM, kfM, DD, vM, DD, Nmeta, svec);
  }
}

// Big-graph Q gemm (1 phase), runs AFTER learner2:
// q[gr] = (feat[gr] @ Wq) * (base_n2 + p2mn[mnid[gr]])   (node-major bf16)
// p2mn gather happens here (no kv stream competing -> L2-hot, near-free).
__global__ __launch_bounds__(256) void gemm_q1(
    const unsigned short* __restrict__ Ab, const unsigned short* __restrict__ Bt,
    unsigned short* __restrict__ Cq, int M,
    const float* __restrict__ svec, const float* __restrict__ P2,
    const int* __restrict__ gidx)
{
  __shared__ __align__(16) unsigned short Asb[64*128];
  __shared__ __align__(16) unsigned short Btb[16896];
  const int tid = threadIdx.x;
  const int wave = tid >> 6, lane = tid & 63;
  const int row0 = blockIdx.x * 64;

  {
    int n4 = lane >> 4, c = lane & 15;
#pragma unroll
    for (int op=0; op<4; op++){
      int rA = wave*16 + op*4;
      int n = rA + n4;
      int gr = row0 + n; if (gr >= M) gr = M - 1;
      gll16((const char*)Ab + (size_t)gr*256 + ((size_t)((c ^ (n & 7)) << 4)),
            &Asb[rA*128]);
    }
    }
  {
    int n4 = lane >> 4, c = lane & 15;
#pragma unroll
    for (int op=0; op<8; op++){
      int rB = wave*32 + op*4;
      int n = rB + n4;
      gll16((const char*)Bt + (size_t)n*256 + ((size_t)((c ^ (n & 7)) << 4)),
            &Btb[rB*128]);
    }
  }
  __syncthreads();

  f32x4 acc[8];
#pragma unroll
  for (int t=0;t<8;t++) acc[t] = (f32x4){0.f,0.f,0.f,0.f};
  const int am = (lane & 15), kq = (lane >> 4) * 8, axr = (am & 7) << 3;
#pragma unroll
  for (int k0=0;k0<128;k0+=32){
    int xo = (k0 + kq) ^ axr;
    bf16x8 a = *(bf16x8*)&Asb[(wave*16 + am)*128 + xo];
#pragma unroll
    for (int t=0;t<8;t++){
      bf16x8 b = *(bf16x8*)&Btb[(t*16 + am)*128 + xo];
      acc[t] = __builtin_amdgcn_mfma_f32_16x16x32_bf16(a, b, acc[t], 0,0,0);
    }
  }
  __syncthreads();
  float* Cls = (float*)Btb;
  {
    int rr = wave*16 + (lane>>4)*4;
    int cc = lane & 15;
#pragma unroll
    for (int t=0;t<8;t++)
#pragma unroll
      for (int r=0;r<4;r++)
        Cls[(rr + r)*CPAD + t*16 + cc] = acc[t][r];
  }
  __syncthreads();
  {
    int r = tid >> 2, cb = (tid & 3) * 32;
    int gr = row0 + r;
    if (gr < M){
      int g = gidx[gr];
      const float* p = P2 + (size_t)g*DD;
#pragma unroll
      for (int j=0;j<8;j++){
        int c = cb + j*4;
        float4 o = *(float4*)&Cls[r*CPAD + c];
        o.x*=(svec[c+0]+p[c+0]); o.y*=(svec[c+1]+p[c+1]);
        o.z*=(svec[c+2]+p[c+2]); o.w*=(svec[c+3]+p[c+3]);
        us4 ob; ob.x=f2b(o.x); ob.y=f2b(o.y); ob.z=f2b(o.z); ob.w=f2b(o.w);
        *(us4*)(Cq + (size_t)gr*DD + c) = ob;
      }
    }
  }
}

// Static param-name graph -> base params.  (k_detect fused in.)
__global__ __launch_bounds__(256) void k_static(
    const void* __restrict__ emb, const int* __restrict__ svals,
    const int* __restrict__ ssrc, const int* __restrict__ sdst,
    const void* __restrict__ u, const void* __restrict__ W2,
    const void* __restrict__ W1, float* __restrict__ base, int nsrc,
    int* __restrict__ dflag)
{
  __shared__ float sagg[15][128];
  __shared__ float ssc[15][16];
  __shared__ float sww[15][16];
  __shared__ int swf;
  const int t = threadIdx.x;
  if (t < 64){
    float m = 0.f;
    for (int i=t; i<128; i+=64){
      float x = fabsf(b2f(((const unsigned short*)emb)[i]));
      if (x < 1e30f) m = fmaxf(m, x);
    }
#pragma unroll
    for (int s=1;s<64;s<<=1) m = fmaxf(m, __shfl_xor(m, s, 64));
    if (t==0){ int f = (m > 1e4f) ? 1 : 0; *dflag = f; swf = f; }
  }
  for (int i=t;i<15*128;i+=256) ((float*)sagg)[i]=0.f;
  __syncthreads();
  const bool wf32 = (swf != 0);
  if (t < 128){
    for (int i=0;i<nsrc;i++){
      int row = sdst[i]; int vr = svals[ssrc[i]];
      sagg[row][t] += gld(emb, (size_t)vr*DD + t, wf32);
    }
  }
  __syncthreads();
  if (t < 240){
    int n = t>>4, l = t&15;
    float a=0.f;
    for (int d=0;d<128;d++) a += sagg[n][d]*gld(u, l*128+d, wf32);
    ssc[n][l] = a * 0.08838834764831845f;
  }
  __syncthreads();
  if (t < 15){
    float mx=-1e30f;
    for (int l=0;l<16;l++) mx = fmaxf(mx, ssc[t][l]);
    float s=0.f;
    for (int l=0;l<16;l++){ float e=__expf(ssc[t][l]-mx); sww[t][l]=e; s+=e; }
    float inv = 1.f/s;
    for (int l=0;l<16;l++) sww[t][l]*=inv;
  }
  __syncthreads();
  if (t < 8){
    float a=0.f,b=0.f,c=0.f;
    for (int l=0;l<16;l++){
      float wv = gld(W1, l*8+t, wf32);
      a += sww[0][l]*wv; b += sww[3][l]*wv; c += sww[9][l]*wv;
    }
    base[t]=a; base[8+t]=b; base[16+t]=c;
  }
  if (t < 128){
    float a=0.f,b=0.f;
    for (int l=0;l<16;l++){
      float wv = gld(W2, l*128+t, wf32);
      a += sww[6][l]*wv; b += sww[12][l]*wv;
    }
    base[24+t]=a; base[152+t]=b;
  }
}

// Merged gather: big graph rows -> bf16 feat; meta rows -> f32 meta_feat.
__global__ __launch_bounds__(256) void gather_rows2(
    const void* __restrict__ emb,
    const int* __restrict__ valsB, unsigned short* __restrict__ featB, int nB,
    const int* __restrict__ valsM, float* __restrict__ featM, int nM,
    const int* __restrict__ dflag)
{
  const bool wf32 = (*dflag) != 0;
  int i = blockIdx.x*256 + threadIdx.x;
  bool big = (i < nB*16);
  int i2 = big ? i : (i - nB*16);
  if (!big && i2 >= nM*16) return;
  int r = i2>>4, c = (i2&15)*8;
  int vr = big ? valsB[r] : valsM[r];
  float vb[8];
  if (wf32){
    float4 f0 = *(const float4*)((const float*)emb + (size_t)vr*DD + c);
    float4 f1 = *(const float4*)((const float*)emb + (size_t)vr*DD + c + 4);
    vb[0]=f0.x; vb[1]=f0.y; vb[2]=f0.z; vb[3]=f0.w;
    vb[4]=f1.x; vb[5]=f1.y; vb[6]=f1.z; vb[7]=f1.w;
  } else {
    uint4 raw = *(const uint4*)((const unsigned short*)emb + (size_t)vr*DD + c);
    const unsigned short* hw = (const unsigned short*)&raw;
#pragma unroll
    for (int j=0;j<8;j++) vb[j] = b2f(hw[j]);
  }
  if (big){
    unsigned short* d = featB + (size_t)r*DD + c;
    us4 o0, o1;
    o0.x=f2b(vb[0]); o0.y=f2b(vb[1]); o0.z=f2b(vb[2]); o0.w=f2b(vb[3]);
    o1.x=f2b(vb[4]); o1.y=f2b(vb[5]); o1.z=f2b(vb[6]); o1.w=f2b(vb[7]);
    *(us4*)d = o0; *(us4*)(d+4) = o1;
  } else {
    float* d = featM + (size_t)r*DD + c;
    *(float4*)d     = make_float4(vb[0],vb[1],vb[2],vb[3]);
    *(float4*)(d+4) = make_float4(vb[4],vb[5],vb[6],vb[7]);
  }
}

__global__ __launch_bounds__(256) void zeroi(int* __restrict__ p, int n){
  int i = blockIdx.x*256 + threadIdx.x;
  if (i < n) p[i] = 0;
}

// ---------------- merged CSR build (big + meta graphs) ----------------
__global__ __launch_bounds__(256) void k_hist2(
    const int* __restrict__ dstB, const int* __restrict__ dstM,
    int* __restrict__ degB, int* __restrict__ degM, int E, int ME, int nbE){
  int b = blockIdx.x, t = threadIdx.x;
  if (b < nbE){ int i = b*256+t; if (i < E) atomicAdd(&degB[dstB[i]], 1); }
  else { int i = (b-nbE)*256+t; if (i < ME) atomicAdd(&degM[dstM[i]], 1); }
}

__global__ __launch_bounds__(256) void k_scan1b(
    const int* __restrict__ degB, int* __restrict__ rpB, int* __restrict__ bsB,
    int nB, int nbB,
    const int* __restrict__ degM, int* __restrict__ rpM, int* __restrict__ bsM,
    int nM){
  __shared__ int ls[256];
  int blk = blockIdx.x, t = threadIdx.x;
  const int* deg; int* rowptr; int* bsum; int n; int b;
  if (blk < nbB){ deg=degB; rowptr=rpB; bsum=bsB; n=nB; b=blk; }
  else          { deg=degM; rowptr=rpM; bsum=bsM; n=nM; b=blk-nbB; }
  int base = b*1024 + t*4;
  int v0 = (base+0<n)?deg[base+0]:0;
  int v1 = (base+1<n)?deg[base+1]:0;
  int v2 = (base+2<n)?deg[base+2]:0;
  int v3 = (base+3<n)?deg[base+3]:0;
  int tsum = v0+v1+v2+v3;
  ls[t] = tsum; __syncthreads();
  for (int o=1;o<256;o<<=1){
    int x = (t>=o) ? ls[t-o] : 0;
    __syncthreads();
    ls[t] += x;
    __syncthreads();
  }
  int excl = ls[t]-tsum;
  if (t==255) bsum[b] = ls[255];
  if (base+0<n) rowptr[base+0]=excl;
  if (base+1<n) rowptr[base+1]=excl+v0;
  if (base+2<n) rowptr[base+2]=excl+v0+v1;
  if (base+3<n) rowptr[base+3]=excl+v0+v1+v2;
}

// scan3 with in-block prefix of block sums (scan2 merged in).
__global__ __launch_bounds__(256) void k_scan3b(
    int* __restrict__ rpB, const int* __restrict__ bsB, int* __restrict__ curB,
    int nB, int nb3B, int nbsB,
    int* __restrict__ rpM, const int* __restrict__ bsM, int* __restrict__ curM,
    int nM, int nbsM){
  __shared__ int spre;
  int blk = blockIdx.x, t = threadIdx.x;
  if (blk < nb3B){
    if (t == 0){
      int chunk = blk >> 2;
      int pre = 0;
      for (int j=0;j<chunk;j++) pre += bsB[j];
      spre = pre;
      if (blk == 0){
        int tot = 0;
        for (int j=0;j<nbsB;j++) tot += bsB[j];
        rpB[nB] = tot;
      }
    }
    __syncthreads();
    int i = blk*256 + t;
    if (i < nB){ int r = rpB[i] + spre; rpB[i] = r; curB[i] = r; }
  } else {
    int b2 = blk - nb3B;
    if (t == 0){
      int chunk = b2 >> 2;
      int pre = 0;
      for (int j=0;j<chunk;j++) pre += bsM[j];
      spre = pre;
      if (b2 == 0){
        int tot = 0;
        for (int j=0;j<nbsM;j++) tot += bsM[j];
        rpM[nM] = tot;
      }
    }
    __syncthreads();
    int i = b2*256 + t;
    if (i < nM){ int r = rpM[i] + spre; rpM[i] = r; curM[i] = r; }
  }
}

// scatter. Big graph: pack (src | meid<<17) into one int.
__global__ __launch_bounds__(256) void k_scatter2(
    const int* __restrict__ dstB, const int* __restrict__ srcB,
    const int* __restrict__ auxB, int* __restrict__ curB,
    int* __restrict__ epackB, int E, int nbE,
    const int* __restrict__ dstM, const int* __restrict__ srcM,
    int* __restrict__ curM, int* __restrict__ esrcM, int* __restrict__ eauxM,
    int ME){
  int blk = blockIdx.x, t = threadIdx.x;
  if (blk < nbE){
    int e = blk*256 + t;
    if (e < E){
      int p = atomicAdd(&curB[dstB[e]], 1);
      epackB[p] = srcB[e] | (auxB[e] << 17);
    }
  } else {
    int e = (blk-nbE)*256 + t;
    if (e < ME){
      int p = atomicAdd(&curM[dstM[e]], 1);
      esrcM[p] = srcM[e];
      eauxM[p] = e;
    }
  }
}

// ---------------- meta-graph edges: CSR, atomic-free, writes mef ----------------
// agg written PRE-NORMALIZED (softmax denominator folded in here).
__global__ __launch_bounds__(256) void edge_meta_csr(
    const int* __restrict__ rowptr, const int* __restrict__ esrc,
    const int* __restrict__ eorig,
    const unsigned short* __restrict__ qm, const unsigned short* __restrict__ kfm,
    const unsigned short* __restrict__ vm,
    const float* __restrict__ base, unsigned short* __restrict__ mef,
    float* __restrict__ agg, int NM)
{
  int d = blockIdx.x*4 + (threadIdx.x>>6);
  if (d >= NM) return;
  int lane = threadIdx.x & 63;
  const float* be2 = base+152; const float* be1 = base+16; const float* bn1 = base+8;
  size_t dq = (size_t)d*DD;
  float q0 = b2f(qm[dq+lane]), q1 = b2f(qm[dq+64+lane]);
  float w0 = be2[lane], w1 = be2[64+lane];
  int h0 = lane>>4, h1 = h0+4;
  float bias0 = be1[h0] + bn1[h0];
  float bias1 = be1[h1] + bn1[h1];
  float z0=0.f, z1=0.f, a0=0.f, a1=0.f;
  int i0 = rowptr[d], i1 = rowptr[d+1];
  for (int i=i0; i<i1; i++){
    int s = esrc[i], e = eorig[i];
    size_t so=(size_t)s*DD, eo=(size_t)e*DD;
    float ke0 = b2f(kfm[so+lane])    * w0;
    float ke1 = b2f(kfm[so+64+lane]) * w1;
    mef[eo+lane]=f2b(ke0); mef[eo+64+lane]=f2b(ke1);
    float p0 = q0*ke0, p1 = q1*ke1;
#pragma unroll
    for (int m=1;m<16;m<<=1){ p0 += __shfl_xor(p0,m,64); p1 += __shfl_xor(p1,m,64); }
    float e0 = __expf(p0*0.25f + bias0);
    float e1 = __expf(p1*0.25f + bias1);
    z0 += e0; z1 += e1;
    a0 += e0*b2f(vm[so+lane]);
    a1 += e1*b2f(vm[so+64+lane]);
  }
  float inv0 = 1.f/(z0 + 1e-9f);
  float inv1 = 1.f/(z1 + 1e-9f);
  agg[dq+lane]    = a0*inv0;
  agg[dq+64+lane] = a1*inv1;
}

// Fused meta-learner over [meta_out (Ma rows, f32) | mef (bf16)].
// 4 rows per block; u/W2/W1 columns cached in registers across rows.
__global__ __launch_bounds__(128) void learner2(
    const float* __restrict__ Xa, const unsigned short* __restrict__ Xb,
    int Ma, int Mtot,
    const void* __restrict__ u, const void* __restrict__ W2,
    const void* __restrict__ W1,
    float* __restrict__ p2a, float* __restrict__ p1a,
    unsigned short* __restrict__ w2me, unsigned short* __restrict__ p1b,
    const float* __restrict__ base, const int* __restrict__ dflag)
{
  __shared__ float sX[128];
  __shared__ float st[16];
  __shared__ float sw[16];
  const bool wf32 = (*dflag) != 0;
  const int t = threadIdx.x;
  const int l = t>>3, j = t&7;
  float uc[16], w2c[16], w1c[16];
#pragma unroll
  for (int m=0;m<16;m++) uc[m] = gld(u, (size_t)l*128 + j*16 + m, wf32);
#pragma unroll
  for (int i=0;i<16;i++) w2c[i] = gld(W2, (size_t)i*128 + t, wf32);
  if (t < 8){
#pragma unroll
    for (int i=0;i<16;i++) w1c[i] = gld(W1, (size_t)i*8 + t, wf32);
  }
  for (int rr=0; rr<4; rr++){
    int row = blockIdx.x*4 + rr;
    if (row >= Mtot) break;
    const bool isB = (row >= Ma);
    const int m = isB ? (row - Ma) : row;
    if (isB) sX[t] = b2f(Xb[(size_t)m*DD + t]);
    else     sX[t] = Xa[(size_t)m*DD + t];
    __syncthreads();
    float part = 0.f;
#pragma unroll
    for (int mm=0;mm<16;mm++) part += sX[j*16+mm]*uc[mm];
    part += __shfl_xor(part,1,64); part += __shfl_xor(part,2,64); part += __shfl_xor(part,4,64);
    if (j==0) st[l] = part * 0.08838834764831845f;
    __syncthreads();
    float mx=-1e30f;
    for (int i=0;i<16;i++) mx = fmaxf(mx, st[i]);
    float ssum=0.f;
    for (int i=0;i<16;i++) ssum += __expf(st[i]-mx);
    float inv = 1.f/ssum;
    if (t<16) sw[t] = __expf(st[t]-mx)*inv;
    __syncthreads();
    float a=0.f;
#pragma unroll
    for (int i=0;i<16;i++) a += sw[i]*w2c[i];
    if (isB) w2me[(size_t)m*DD+t] = f2b(base[152+t] + a);
    else     p2a[(size_t)m*DD+t] = a;
    if (t<8){
      float bb=0.f;
#pragma unroll
      for (int i=0;i<16;i++) bb += sw[i]*w1c[i];
      if (isB) p1b[(size_t)m*HH+t] = f2b(bb);
      else     p1a[(size_t)m*HH+t] = bb;
    }
    __syncthreads();
  }
}

// ---------------- big-graph: fused scores+agg, fp8 kv, packed indices ----------
// R2-form (best measured: 65.5us, FETCH=E*256 minimal, 3.5 TB/s): one 16-lane
// group per dst node, natural node order, q PRE-SCALED (gemm_q1), node-major
// 256B kv rows fully consumed per edge. agg PRE-NORMALIZED (0.125 fp8
// v-descale folded into 1/z).
__global__ __launch_bounds__(256) void edge_fused(
    const int* __restrict__ rowptr, const int* __restrict__ epack,
    const int* __restrict__ mnid,
    const unsigned short* __restrict__ q, const unsigned char* __restrict__ kv8,
    const unsigned short* __restrict__ w2me, const unsigned short* __restrict__ p1me,
    const float* __restrict__ p1mn, const float* __restrict__ base,
    unsigned short* __restrict__ aggb, int N)
{
  int wv = blockIdx.x*4 + (threadIdx.x>>6);
  int lane = threadIdx.x & 63;
  int grp = lane >> 4, l16 = lane & 15;
  int d = wv*4 + grp;                 // each 16-lane group owns one dst node
  if (d >= N) return;
  int c8 = l16 * 8;
  int h = l16 >> 1;

  int i0 = rowptr[d], i1 = rowptr[d+1];
  float bias = base[16+h] + base[8+h] + p1mn[(size_t)mnid[d]*HH + h];
  size_t dq = (size_t)d*DD;
  float qv[8];
  {
    uint4 qraw = *(const uint4*)(q + dq + c8);
    const unsigned short* qh = (const unsigned short*)&qraw;
#pragma unroll
    for (int j=0;j<8;j++) qv[j] = b2f(qh[j])*0.03125f;  // 0.25 * 1/8 (k fp8 scale)
  }

  float zh = 0.f;
  float a[8];
#pragma unroll
  for (int j=0;j<8;j++) a[j] = 0.f;

  int i = i0;
  for (; i + 1 < i1; i += 2){
    unsigned int v0p = (unsigned int)epack[i];
    unsigned int v1p = (unsigned int)epack[i+1];
    int s0 = v0p & 0x1FFFF, me0 = v0p >> 17;
    int s1 = v1p & 0x1FFFF, me1 = v1p >> 17;
    const unsigned char* kv0 = kv8 + (size_t)s0*256 + c8;
    const unsigned char* kv1 = kv8 + (size_t)s1*256 + c8;
    uint2 kraw0 = *(const uint2*)kv0;
    uint2 vraw0 = *(const uint2*)(kv0 + 128);
    uint4 wraw0 = *(const uint4*)(w2me + (size_t)me0*DD + c8);
    float pm0 = b2f(p1me[(size_t)me0*HH + h]);
    uint2 kraw1 = *(const uint2*)kv1;
    uint2 vraw1 = *(const uint2*)(kv1 + 128);
    uint4 wraw1 = *(const uint4*)(w2me + (size_t)me1*DD + c8);
    float pm1 = b2f(p1me[(size_t)me1*HH + h]);
    float k0f[8], v0f[8], k1f[8], v1f[8];
    cvt4(kraw0.x, k0f); cvt4(kraw0.y, k0f+4);
    cvt4(vraw0.x, v0f); cvt4(vraw0.y, v0f+4);
    cvt4(kraw1.x, k1f); cvt4(kraw1.y, k1f+4);
    cvt4(vraw1.x, v1f); cvt4(vraw1.y, v1f+4);
    const unsigned short* wh0 = (const unsigned short*)&wraw0;
    const unsigned short* wh1 = (const unsigned short*)&wraw1;
    float pA = 0.f, pB = 0.f;
#pragma unroll
    for (int j=0;j<8;j++){
      pA += qv[j]*(k0f[j]*b2f(wh0[j]));
      pB += qv[j]*(k1f[j]*b2f(wh1[j]));
    }
    pA += __shfl_xor(pA, 1, 64);
    pB += __shfl_xor(pB, 1, 64);
    float ex0 = __expf(pA + bias + pm0);
    float ex1 = __expf(pB + bias + pm1);
    zh += ex0 + ex1;
#pragma unroll
    for (int j=0;j<8;j++) a[j] += ex0*v0f[j] + ex1*v1f[j];
  }
  if (i < i1){
    unsigned int vp = (unsigned int)epack[i];
    int s = vp & 0x1FFFF, me = vp >> 17;
    const unsigned char* kv = kv8 + (size_t)s*256 + c8;
    uint2 kraw = *(const uint2*)kv;
    uint2 vraw = *(const uint2*)(kv + 128);
    uint4 wraw = *(const uint4*)(w2me + (size_t)me*DD + c8);
    float pm = b2f(p1me[(size_t)me*HH + h]);
    float kf[8], vf[8];
    cvt4(kraw.x, kf); cvt4(kraw.y, kf+4);
    cvt4(vraw.x, vf); cvt4(vraw.y, vf+4);
    const unsigned short* wh = (const unsigned short*)&wraw;
    float p = 0.f;
#pragma unroll
    for (int j=0;j<8;j++) p += qv[j]*(kf[j]*b2f(wh[j]));
    p += __shfl_xor(p, 1, 64);
    float ex = __expf(p + bias + pm);
    zh += ex;
#pragma unroll
    for (int j=0;j<8;j++) a[j] += ex*vf[j];
  }

  // each lane owns its 8 channels; zh is per-head (same in both pair lanes)
  float inv = 0.125f / (zh + 1e-9f);   // fp8 v-descale folded into 1/z
  us8 o;
#pragma unroll
  for (int j=0;j<8;j++) o.s[j] = f2b(a[j]*inv);
  *(us8*)(aggb + dq + c8) = o;
}

// One 16-lane group per target; vectorized feat row read + shuffle reduce.
__global__ __launch_bounds__(256) void readout(
    const int* __restrict__ tgt, const int* __restrict__ mnid,
    const unsigned short* __restrict__ featb, const float* __restrict__ p1mn,
    const float* __restrict__ base, float* __restrict__ acc,
    void* __restrict__ out, int last, float invNB, int BT,
    const int* __restrict__ dflag)
{
  int t = blockIdx.x*256 + threadIdx.x;
  int ti = t >> 4, l16 = t & 15;
  if (ti >= BT) return;
  int idx = tgt[ti]; int mn = mnid[idx];
  int h = l16 >> 1;
  float tw = base[h] + p1mn[(size_t)mn*HH + h];
  uint4 raw = *(const uint4*)(featb + (size_t)idx*DD + l16*8);
  const unsigned short* hw = (const unsigned short*)&raw;
  float s = 0.f;
#pragma unroll
  for (int j=0;j<8;j++) s += b2f(hw[j]);
  float part = tw * s;
  part += __shfl_xor(part, 1, 64);
  part += __shfl_xor(part, 2, 64);
  part += __shfl_xor(part, 4, 64);
  part += __shfl_xor(part, 8, 64);
  if (l16 == 0){
    if (!last) acc[ti] = part;
    else {
      float r = (acc[ti] + part) * invNB;
      if ((*dflag) != 0) ((float*)out)[ti] = r;
      else ((__hip_bfloat16*)out)[ti] = __float2bfloat16(r);
    }
  }
}

extern "C" void kernel_launch(void* const* d_in, const int* in_sizes, int n_in,
                              void* d_out, int out_size, void* d_ws, size_t ws_size,
                              hipStream_t stream) {
  const void* emb   = d_in[0];
  const void* u     = d_in[1];
  const void* W2lat = d_in[2];
  const void* W1lat = d_in[3];
  WPtrs wptrs;
  for (int i=0;i<8;i++) wptrs.p[i] = d_in[4+i];
  const int* node_vals      = (const int*)d_in[12];
  const int* meta_node_vals = (const int*)d_in[13];
  const int* src            = (const int*)d_in[14];
  const int* dst            = (const int*)d_in[15];
  const int* meta_src       = (const int*)d_in[16];
  const int* meta_dst       = (const int*)d_in[17];
  const int* meta_node_id   = (const int*)d_in[18];
  const int* meta_edge_id   = (const int*)d_in[19];
  const int* target_idx     = (const int*)d_in[20];
  const int* static_vals    = (const int*)d_in[21];
  const int* static_src     = (const int*)d_in[22];
  const int* static_dst     = (const int*)d_in[23];

  const int N  = in_sizes[12];
  const int MN = in_sizes[13];
  const int E  = in_sizes[14];
  const int ME = in_sizes[16];
  const int BT = in_sizes[20];
  const int NSRC = in_sizes[22];
  const int NB = in_sizes[8] / (DD*DD);

  float* ws = (float*)d_ws;
  size_t off = 0;
  // keep every allocation 16B-aligned (global_load_lds sources need it)
  auto allocf = [&](size_t n){ float* p = ws + off; off += (n + 3) & ~(size_t)3; return p; };
  auto allocb = [&](size_t n){ unsigned short* p = (unsigned short*)(ws + off); off += (((n+1)/2) + 3) & ~(size_t)3; return p; };
  auto alloci = [&](size_t n){ int* p = (int*)(ws + off); off += (n + 3) & ~(size_t)3; return p; };
  int*            dflag = (int*)ws; off += 4;
  unsigned short* feat  = allocb((size_t)N*DD);
  unsigned short* q     = allocb((size_t)N*DD);
  unsigned char*  kv8   = (unsigned char*)allocf((size_t)N*64);  // N x 256B fp8 rows
  unsigned short* aggb  = allocb((size_t)N*DD);
  float*          meta_feat= allocf((size_t)MN*DD);
  float*          agg_m = allocf((size_t)MN*DD);
  unsigned short* q_m   = allocb((size_t)MN*DD);
  unsigned short* kf_m  = allocb((size_t)MN*DD);
  unsigned short* v_m   = allocb((size_t)MN*DD);
  float*          meta_out = allocf((size_t)MN*DD);
  unsigned short* mef   = allocb((size_t)ME*DD);
  float*          p2mn  = allocf((size_t)MN*DD);
  float*          p1mn  = allocf((size_t)MN*HH);
  unsigned short* w2me  = allocb((size_t)ME*DD);
  unsigned short* p1me  = allocb((size_t)ME*HH);
  float*          base  = allocf(280);
  float*          acc   = allocf((size_t)BT);
  unsigned short* wstage= allocb((size_t)8*NB*DD*DD);
  int*            rowptr= alloci((size_t)N+1);
  int*            cursor= alloci((size_t)N);
  int*            epack = alloci((size_t)E);
  int*            rowptr_m= alloci((size_t)MN+1);
  int*            cursor_m= alloci((size_t)MN);
  int*            esrc_m  = alloci((size_t)ME);
  int*            eorig_m = alloci((size_t)ME);
  int*            degAll  = alloci((size_t)(N+MN));
  int*            deg     = degAll;
  int*            deg_m   = degAll + N;
  const int nb_scan   = (N + 1023)/1024;
  const int nb_scan_m = (MN + 1023)/1024;
  int*            bsum   = alloci((size_t)nb_scan);
  int*            bsum_m = alloci((size_t)nb_scan_m);
  (void)ws_size; (void)n_in; (void)out_size;

  const float* base_n2 = base + 24;

  k_static<<<1,256,0,stream>>>(emb, static_vals, static_src, static_dst,
                               u, W2lat, W1lat, base, NSRC, dflag);
  gather_rows2<<<((N+MN)*16+255)/256,256,0,stream>>>(emb, node_vals, feat, N,
      meta_node_vals, meta_feat, MN, dflag);

  const int nbE  = (E+255)/256, nbME = (ME+255)/256;
  const int nb3B = (N+255)/256, nb3M = (MN+255)/256;
  zeroi<<<(N+MN+255)/256,256,0,stream>>>(degAll, N+MN);
  k_hist2<<<nbE+nbME,256,0,stream>>>(dst, meta_dst, deg, deg_m, E, ME, nbE);
  k_scan1b<<<nb_scan+nb_scan_m,256,0,stream>>>(deg, rowptr, bsum, N, nb_scan,
      deg_m, rowptr_m, bsum_m, MN);
  k_scan3b<<<nb3B+nb3M,256,0,stream>>>(rowptr, bsum, cursor, N, nb3B, nb_scan,
      rowptr_m, bsum_m, cursor_m, MN, nb_scan_m);
  k_scatter2<<<nbE+nbME,256,0,stream>>>(dst, src, meta_edge_id, cursor,
      epack, E, nbE, meta_dst, meta_src, cursor_m, esrc_m, eorig_m, ME);

  w_repack16<<<8*NB*64,256,0,stream>>>(wptrs, wstage, NB, dflag);

  const int gm = (MN+63)/64;
  const int gN = (N+63)/64;
  const float invNB = 1.0f/(float)NB;

  for (int b=0;b<NB;b++){
    const unsigned short* wq_m = wstage + (size_t)(0*NB+b)*DD*DD;
    const unsigned short* wk_m = wstage + (size_t)(1*NB+b)*DD*DD;
    const unsigned short* wv_m = wstage + (size_t)(2*NB+b)*DD*DD;
    const unsigned short* wo_m = wstage + (size_t)(3*NB+b)*DD*DD;
    const unsigned short* wqb  = wstage + (size_t)(4*NB+b)*DD*DD;
    const unsigned short* wkb  = wstage + (size_t)(5*NB+b)*DD*DD;
    const unsigned short* wvb  = wstage + (size_t)(6*NB+b)*DD*DD;
    const unsigned short* wob  = wstage + (size_t)(7*NB+b)*DD*DD;

    // ---- merged big-KV + meta-QKV (no meta-chain dependency) ----
    gemm_qkv2<<<gN+gm,256,0,stream>>>(feat, meta_feat,
        wkb, wvb, wq_m, wk_m, wv_m,
        kv8, q_m, kf_m, v_m, N, MN, gN, base_n2);

    // ---- meta conv (CSR, atomic-free) ----
    edge_meta_csr<<<(MN+3)/4,256,0,stream>>>(rowptr_m, esrc_m, eorig_m,
        q_m, kf_m, v_m, base, mef, agg_m, MN);
    // meta Wo: meta_out = relu(agg_m@Wo) (f32, agg pre-normalized); meta_feat += relu
    gemm128m<EPI_RELU_RES2,false,false><<<gm,256,0,stream>>>(agg_m, wo_m,
        meta_out, MN, nullptr, meta_feat, meta_feat);
    // wide fused learners: MN rows (f32 meta_out) + ME rows (bf16 mef)
    learner2<<<(MN+ME+3)/4,128,0,stream>>>(meta_out, mef, MN, MN+ME,
        u, W2lat, W1lat, p2mn, p1mn, w2me, p1me, base, dflag);

    // ---- big Q gemm with head-scale gather (p2mn L2-hot here) ----
    gemm_q1<<<gN,256,0,stream>>>(feat, wqb, q, N, base_n2, p2mn, meta_node_id);

    // ---- big conv (R2 form: minimal bytes, max random-access BW) ----
    edge_fused<<<(N+15)/16,256,0,stream>>>(rowptr, epack,
        meta_node_id, q, kv8, w2me, p1me, p1mn, base, aggb, N);
    gemm128m<EPI_RELU_RES,true,true><<<gN,256,0,stream>>>(aggb, wob, feat, N,
        feat, nullptr, nullptr);

    // ---- readout ----
    readout<<<(BT*16+255)/256,256,0,stream>>>(target_idx, meta_node_id, feat, p1mn,
        base, acc, d_out, (b==NB-1) ? 1 : 0, invNB, BT, dflag);
  }
}

// Round 9
// 554.663 us; speedup vs baseline: 1.3882x; 1.0713x over previous
//
#include <hip/hip_runtime.h>
#include <hip/hip_bf16.h>
#include <hip/hip_fp8.h>

#define DD   128
#define HH   8

typedef short bf16x8 __attribute__((ext_vector_type(8)));
typedef float f32x4  __attribute__((ext_vector_type(4)));
typedef float f32x2  __attribute__((ext_vector_type(2)));

__device__ __forceinline__ float b2f(unsigned short v){
  union { unsigned int u; float f; } x; x.u = ((unsigned int)v) << 16; return x.f;
}
__device__ __forceinline__ unsigned short f2b(float f){
  __hip_bfloat16 h = __float2bfloat16(f);
  return *(unsigned short*)&h;
}
__device__ __forceinline__ unsigned char f2f8(float x){
  __hip_fp8_e4m3 h(x);
  return h.__x;
}
__device__ __forceinline__ float f82f(unsigned char b){
  __hip_fp8_e4m3 h; h.__x = b;
  return (float)h;
}
// 4 fp8 bytes (one u32) -> 4 floats; HW packed cvt when available.
__device__ __forceinline__ void cvt4(unsigned int w, float* o){
#if defined(__has_builtin)
# if __has_builtin(__builtin_amdgcn_cvt_pk_f32_fp8)
  f32x2 lo = __builtin_amdgcn_cvt_pk_f32_fp8((int)w, false);
  f32x2 hi = __builtin_amdgcn_cvt_pk_f32_fp8((int)w, true);
  o[0]=lo[0]; o[1]=lo[1]; o[2]=hi[0]; o[3]=hi[1];
  return;
# endif
#endif
  o[0]=f82f(w&0xff); o[1]=f82f((w>>8)&0xff);
  o[2]=f82f((w>>16)&0xff); o[3]=f82f((w>>24)&0xff);
}
struct __align__(8) us4 { unsigned short x,y,z,w; };
struct __align__(16) us8 { unsigned short s[8]; };

__device__ __forceinline__ float gld(const void* p, size_t i, bool f32){
  if (f32) return ((const float*)p)[i];
  return b2f(((const unsigned short*)p)[i]);
}

// async global->LDS, 16B per lane (wave-uniform LDS base + lane*16)
__device__ __forceinline__ void gll16(const void* g, void* l){
  __builtin_amdgcn_global_load_lds(
      (const __attribute__((address_space(1))) unsigned int*)g,
      (__attribute__((address_space(3))) unsigned int*)l, 16, 0, 0);
}

struct WPtrs { const void* p[8]; };

enum { EPI_STORE=0, EPI_SCALE_CONST=1, EPI_RELU=3,
       EPI_RELU_RES=4, EPI_RELU_RES2=5 };

#define CPAD 132

// C[M,128] = epi( A[M,128] @ B[128,128] ), B bf16 TRANSPOSED ([n][k]).
// EPI_RELU_RES : C = relu(x) + Rb(bf16) [big Wo, OUTB=1] + FUSED READOUT:
//   rows that are targets (tgt_of chain) accumulate tw.feat into acc[ti].
// EPI_RELU_RES2: Cv = relu(x) f32; C2 = relu(x)+Rf (f32) [meta Wo, OUTB=0]
template<int EPI, bool INB, bool OUTB>
__global__ __launch_bounds__(256) void gemm128m(
    const void* __restrict__ Av, const unsigned short* __restrict__ Bt,
    void* __restrict__ Cv, int M,
    const unsigned short* __restrict__ Rb,
    const float* __restrict__ Rf, float* __restrict__ C2,
    const int* __restrict__ mnid, const float* __restrict__ p1mn,
    const float* __restrict__ base,
    const int* __restrict__ tgt_of, const int* __restrict__ tgt_next,
    float* __restrict__ acc)
{
  __shared__ __align__(16) unsigned short Asb[64*128];
  __shared__ __align__(16) unsigned short Btb[16896];  // B: 32KB / C: 64x132 f32
  const int tid = threadIdx.x;
  const int wave = tid >> 6, lane = tid & 63;
  const int row0 = blockIdx.x * 64;

  if (INB){
    const char* Ab = (const char*)Av;
    int n4 = lane >> 4, c = lane & 15;
#pragma unroll
    for (int op=0; op<4; op++){
      int rA = wave*16 + op*4;
      int n = rA + n4;
      int gr = row0 + n; if (gr >= M) gr = M - 1;
      gll16(Ab + (size_t)gr*256 + ((size_t)((c ^ (n & 7)) << 4)), &Asb[rA*128]);
    }
  } else {
    const float* Af = (const float*)Av;
    int r = tid >> 2, cb = (tid & 3) * 32, rx = (r & 7) << 3;
    int gr = row0 + r;
#pragma unroll
    for (int j=0;j<8;j++){
      int cc = cb + j*4;
      float4 val = make_float4(0.f,0.f,0.f,0.f);
      if (gr < M) val = *(const float4*)(Af + (size_t)gr*DD + cc);
      us4 o; o.x=f2b(val.x); o.y=f2b(val.y); o.z=f2b(val.z); o.w=f2b(val.w);
      *(us4*)&Asb[r*128 + (cc ^ rx)] = o;
    }
  }
  {
    int n4 = lane >> 4, c = lane & 15;
#pragma unroll
    for (int op=0; op<8; op++){
      int rB = wave*32 + op*4;
      int n = rB + n4;
      gll16((const char*)Bt + (size_t)n*256 + ((size_t)((c ^ (n & 7)) << 4)),
            &Btb[rB*128]);
    }
  }
  __syncthreads();

  f32x4 acc0[8];
#pragma unroll
  for (int t=0;t<8;t++) acc0[t] = (f32x4){0.f,0.f,0.f,0.f};
  const int am = (lane & 15), kq = (lane >> 4) * 8, axr = (am & 7) << 3;
#pragma unroll
  for (int k0=0;k0<128;k0+=32){
    int xo = (k0 + kq) ^ axr;
    bf16x8 a = *(bf16x8*)&Asb[(wave*16 + am)*128 + xo];
#pragma unroll
    for (int t=0;t<8;t++){
      bf16x8 b = *(bf16x8*)&Btb[(t*16 + am)*128 + xo];
      acc0[t] = __builtin_amdgcn_mfma_f32_16x16x32_bf16(a, b, acc0[t], 0,0,0);
    }
  }
  __syncthreads();
  float* Cls = (float*)Btb;
  {
    int rr = wave*16 + (lane>>4)*4;
    int cc = lane & 15;
#pragma unroll
    for (int t=0;t<8;t++)
#pragma unroll
      for (int r=0;r<4;r++)
        Cls[(rr + r)*CPAD + t*16 + cc] = acc0[t][r];
  }
  __syncthreads();

  {
    int r = tid >> 2, cb = (tid & 3) * 32;
    int gr = row0 + r;
    if (gr < M){
      float hs0 = 0.f, hs1 = 0.f;
#pragma unroll
      for (int j=0;j<8;j++){
        int c = cb + j*4;
        float4 o = *(float4*)&Cls[r*CPAD + c];
        if (EPI == EPI_RELU_RES){
          us4 rb = *(const us4*)(Rb + (size_t)gr*DD + c);
          o.x=fmaxf(o.x,0.f)+b2f(rb.x); o.y=fmaxf(o.y,0.f)+b2f(rb.y);
          o.z=fmaxf(o.z,0.f)+b2f(rb.z); o.w=fmaxf(o.w,0.f)+b2f(rb.w);
          float s4 = o.x + o.y + o.z + o.w;
          if (j < 4) hs0 += s4; else hs1 += s4;
        } else if (EPI == EPI_RELU_RES2){
          o.x=fmaxf(o.x,0.f); o.y=fmaxf(o.y,0.f); o.z=fmaxf(o.z,0.f); o.w=fmaxf(o.w,0.f);
          float4 rf = *(const float4*)(Rf + (size_t)gr*DD + c);
          *(float4*)(C2 + (size_t)gr*DD + c) =
              make_float4(o.x+rf.x, o.y+rf.y, o.z+rf.z, o.w+rf.w);
        }
        if (OUTB){
          us4 ob; ob.x=f2b(o.x); ob.y=f2b(o.y); ob.z=f2b(o.z); ob.w=f2b(o.w);
          *(us4*)((unsigned short*)Cv + (size_t)gr*DD + c) = ob;
        } else {
          *(float4*)((float*)Cv + (size_t)gr*DD + c) = o;
        }
      }
      if (EPI == EPI_RELU_RES){
        // fused readout: logit partial for this row's 2 heads, reduce 4 lanes,
        // push to acc for each target pointing at this node (chain, rare).
        int hb = cb >> 4;
        int mn = mnid[gr];
        float tw0 = base[hb]     + p1mn[(size_t)mn*HH + hb];
        float tw1 = base[hb + 1] + p1mn[(size_t)mn*HH + hb + 1];
        float part = tw0*hs0 + tw1*hs1;
        part += __shfl_xor(part, 1, 64);
        part += __shfl_xor(part, 2, 64);
        if ((tid & 3) == 0){
          int ti = tgt_of[gr];
          while (ti >= 0){
            atomicAdd(&acc[ti], part);
            ti = tgt_next[ti];
          }
        }
      }
    }
  }
}

// Fused Q/K/V gemm body. FP8KV (big): ph0 -> q bf16 node-major (plain store,
// head scale deferred to edge_fused); ph1/2 -> fp8 (x8) into 256B/row kv buf.
// !FP8KV (meta): 3 phases node-major bf16, q scaled by svec.
template<int EPIQ, bool INB, bool FP8KV>
__device__ __forceinline__ void qkv_body(
    unsigned short* Asb, unsigned short* Btb, int blk,
    const void* __restrict__ Av,
    const unsigned short* __restrict__ Btq, const unsigned short* __restrict__ Btk,
    const unsigned short* __restrict__ Btv,
    void* __restrict__ Cq, void* __restrict__ Ck, int stK,
    void* __restrict__ Cvo, int stV, int M,
    const float* __restrict__ svec)
{
  const int tid = threadIdx.x;
  const int wave = tid >> 6, lane = tid & 63;
  const int row0 = blk * 64;

  if (INB){
    const char* Ab = (const char*)Av;
    int n4 = lane >> 4, c = lane & 15;
#pragma unroll
    for (int op=0; op<4; op++){
      int rA = wave*16 + op*4;
      int n = rA + n4;
      int gr = row0 + n; if (gr >= M) gr = M - 1;
      gll16(Ab + (size_t)gr*256 + ((size_t)((c ^ (n & 7)) << 4)), &Asb[rA*128]);
    }
  } else {
    const float* Af = (const float*)Av;
    int r = tid >> 2, cb = (tid & 3) * 32, rx = (r & 7) << 3;
    int gr = row0 + r;
#pragma unroll
    for (int j=0;j<8;j++){
      int cc = cb + j*4;
      float4 val = make_float4(0.f,0.f,0.f,0.f);
      if (gr < M) val = *(const float4*)(Af + (size_t)gr*DD + cc);
      us4 o; o.x=f2b(val.x); o.y=f2b(val.y); o.z=f2b(val.z); o.w=f2b(val.w);
      *(us4*)&Asb[r*128 + (cc ^ rx)] = o;
    }
  }

  const unsigned short* Bts[3] = {Btq, Btk, Btv};
  void* Cs[3] = {Cq, Ck, Cvo};
  const int sts[3] = {DD, stK, stV};
  const int am = (lane & 15), kq = (lane >> 4) * 8, axr = (am & 7) << 3;

  for (int ph=0; ph<3; ph++){
    {
      const unsigned short* Bt = Bts[ph];
      int n4 = lane >> 4, c = lane & 15;
#pragma unroll
      for (int op=0; op<8; op++){
        int rB = wave*32 + op*4;
        int n = rB + n4;
        gll16((const char*)Bt + (size_t)n*256 + ((size_t)((c ^ (n & 7)) << 4)),
              &Btb[rB*128]);
      }
    }
    __syncthreads();
    f32x4 acc[8];
#pragma unroll
    for (int t=0;t<8;t++) acc[t] = (f32x4){0.f,0.f,0.f,0.f};
#pragma unroll
    for (int k0=0;k0<128;k0+=32){
      int xo = (k0 + kq) ^ axr;
      bf16x8 a = *(bf16x8*)&Asb[(wave*16 + am)*128 + xo];
#pragma unroll
      for (int t=0;t<8;t++){
        bf16x8 b = *(bf16x8*)&Btb[(t*16 + am)*128 + xo];
        acc[t] = __builtin_amdgcn_mfma_f32_16x16x32_bf16(a, b, acc[t], 0,0,0);
      }
    }
    __syncthreads();
    float* Cls = (float*)Btb;
    {
      int rr = wave*16 + (lane>>4)*4;
      int cc = lane & 15;
#pragma unroll
      for (int t=0;t<8;t++)
#pragma unroll
        for (int r=0;r<4;r++)
          Cls[(rr + r)*CPAD + t*16 + cc] = acc[t][r];
    }
    __syncthreads();
    {
      int r = tid >> 2, cb = (tid & 3) * 32;
      int gr = row0 + r;
      if (gr < M){
#pragma unroll
        for (int j=0;j<8;j++){
          int c = cb + j*4;
          float4 o = *(float4*)&Cls[r*CPAD + c];
          if (ph == 0 && EPIQ == EPI_SCALE_CONST){
            o.x*=svec[c+0]; o.y*=svec[c+1]; o.z*=svec[c+2]; o.w*=svec[c+3];
          }
          if (FP8KV && ph > 0){
            unsigned char* Cb = (unsigned char*)Cs[ph];
            uchar4 ob;
            ob.x=f2f8(o.x*8.f); ob.y=f2f8(o.y*8.f);
            ob.z=f2f8(o.z*8.f); ob.w=f2f8(o.w*8.f);
            *(uchar4*)(Cb + (size_t)gr*256 + c) = ob;
          } else {
            us4 ob; ob.x=f2b(o.x); ob.y=f2b(o.y); ob.z=f2b(o.z); ob.w=f2b(o.w);
            *(us4*)((unsigned short*)Cs[ph] + (size_t)gr*sts[ph] + c) = ob;
          }
        }
      }
    }
    __syncthreads();
  }
}

// Merged big+meta QKV in one dispatch: blocks [0,gN) big graph (bf16 in,
// plain q + fp8 kv out); blocks [gN, gN+gm) meta graph (f32 in, scaled q).
__global__ __launch_bounds__(256) void gemm_qkv2(
    const unsigned short* __restrict__ featB, const float* __restrict__ featM,
    const unsigned short* __restrict__ wqb, const unsigned short* __restrict__ wkb,
    const unsigned short* __restrict__ wvb,
    const unsigned short* __restrict__ wqm, const unsigned short* __restrict__ wkm,
    const unsigned short* __restrict__ wvm,
    unsigned short* __restrict__ qB, unsigned char* __restrict__ kv8,
    unsigned short* __restrict__ qM, unsigned short* __restrict__ kfM,
    unsigned short* __restrict__ vM,
    int Nbig, int Nmeta, int gN, const float* __restrict__ svec)
{
  __shared__ __align__(16) unsigned short Asb[64*128];
  __shared__ __align__(16) unsigned short Btb[16896];
  if (blockIdx.x < gN){
    qkv_body<EPI_STORE,true,true>(Asb, Btb, blockIdx.x, featB,
        wqb, wkb, wvb, qB, kv8, 0, kv8 + 128, 0, Nbig, svec);
  } else {
    qkv_body<EPI_SCALE_CONST,false,false>(Asb, Btb, blockIdx.x - gN, featM,
        wqm, wkm, wvm, qM, kfM, DD, vM, DD, Nmeta, svec);
  }
}

// Static param-name graph -> base params.  (k_detect fused in.)
__global__ __launch_bounds__(256) void k_static(
    const void* __restrict__ emb, const int* __restrict__ svals,
    const int* __restrict__ ssrc, const int* __restrict__ sdst,
    const void* __restrict__ u, const void* __restrict__ W2,
    const void* __restrict__ W1, float* __restrict__ base, int nsrc,
    int* __restrict__ dflag)
{
  __shared__ float sagg[15][128];
  __shared__ float ssc[15][16];
  __shared__ float sww[15][16];
  __shared__ int swf;
  const int t = threadIdx.x;
  if (t < 64){
    float m = 0.f;
    for (int i=t; i<128; i+=64){
      float x = fabsf(b2f(((const unsigned short*)emb)[i]));
      if (x < 1e30f) m = fmaxf(m, x);
    }
#pragma unroll
    for (int s=1;s<64;s<<=1) m = fmaxf(m, __shfl_xor(m, s, 64));
    if (t==0){ int f = (m > 1e4f) ? 1 : 0; *dflag = f; swf = f; }
  }
  for (int i=t;i<15*128;i+=256) ((float*)sagg)[i]=0.f;
  __syncthreads();
  const bool wf32 = (swf != 0);
  if (t < 128){
    for (int i=0;i<nsrc;i++){
      int row = sdst[i]; int vr = svals[ssrc[i]];
      sagg[row][t] += gld(emb, (size_t)vr*DD + t, wf32);
    }
  }
  __syncthreads();
  if (t < 240){
    int n = t>>4, l = t&15;
    float a=0.f;
    for (int d=0;d<128;d++) a += sagg[n][d]*gld(u, l*128+d, wf32);
    ssc[n][l] = a * 0.08838834764831845f;
  }
  __syncthreads();
  if (t < 15){
    float mx=-1e30f;
    for (int l=0;l<16;l++) mx = fmaxf(mx, ssc[t][l]);
    float s=0.f;
    for (int l=0;l<16;l++){ float e=__expf(ssc[t][l]-mx); sww[t][l]=e; s+=e; }
    float inv = 1.f/s;
    for (int l=0;l<16;l++) sww[t][l]*=inv;
  }
  __syncthreads();
  if (t < 8){
    float a=0.f,b=0.f,c=0.f;
    for (int l=0;l<16;l++){
      float wv = gld(W1, l*8+t, wf32);
      a += sww[0][l]*wv; b += sww[3][l]*wv; c += sww[9][l]*wv;
    }
    base[t]=a; base[8+t]=b; base[16+t]=c;
  }
  if (t < 128){
    float a=0.f,b=0.f;
    for (int l=0;l<16;l++){
      float wv = gld(W2, l*128+t, wf32);
      a += sww[6][l]*wv; b += sww[12][l]*wv;
    }
    base[24+t]=a; base[152+t]=b;
  }
}

// Merged: big rows -> bf16 feat; meta rows -> f32 meta_feat; weight repack.
__global__ __launch_bounds__(256) void gather_repack(
    const void* __restrict__ emb,
    const int* __restrict__ valsB, unsigned short* __restrict__ featB, int nB,
    const int* __restrict__ valsM, float* __restrict__ featM, int nM,
    WPtrs W, unsigned short* __restrict__ stage, int NBt,
    const int* __restrict__ dflag, int gB)
{
  const bool wf32 = (*dflag) != 0;
  if ((int)blockIdx.x >= gB){
    int bid = blockIdx.x - gB;
    int idx = bid >> 6;
    int ti = idx / NBt, bi = idx - ti*NBt;
    size_t bo = (size_t)bi*DD*DD;
    int i = (bid & 63)*256 + threadIdx.x;
    int k = i >> 7, n = i & 127;
    float x;
    if (wf32) x = ((const float*)W.p[ti])[bo + i];
    else      x = b2f(((const unsigned short*)W.p[ti])[bo + i]);
    stage[(size_t)idx*DD*DD + n*DD + k] = f2b(x);
    return;
  }
  int i = blockIdx.x*256 + threadIdx.x;
  bool big = (i < nB*16);
  int i2 = big ? i : (i - nB*16);
  if (!big && i2 >= nM*16) return;
  int r = i2>>4, c = (i2&15)*8;
  int vr = big ? valsB[r] : valsM[r];
  float vb[8];
  if (wf32){
    float4 f0 = *(const float4*)((const float*)emb + (size_t)vr*DD + c);
    float4 f1 = *(const float4*)((const float*)emb + (size_t)vr*DD + c + 4);
    vb[0]=f0.x; vb[1]=f0.y; vb[2]=f0.z; vb[3]=f0.w;
    vb[4]=f1.x; vb[5]=f1.y; vb[6]=f1.z; vb[7]=f1.w;
  } else {
    uint4 raw = *(const uint4*)((const unsigned short*)emb + (size_t)vr*DD + c);
    const unsigned short* hw = (const unsigned short*)&raw;
#pragma unroll
    for (int j=0;j<8;j++) vb[j] = b2f(hw[j]);
  }
  if (big){
    unsigned short* d = featB + (size_t)r*DD + c;
    us4 o0, o1;
    o0.x=f2b(vb[0]); o0.y=f2b(vb[1]); o0.z=f2b(vb[2]); o0.w=f2b(vb[3]);
    o1.x=f2b(vb[4]); o1.y=f2b(vb[5]); o1.z=f2b(vb[6]); o1.w=f2b(vb[7]);
    *(us4*)d = o0; *(us4*)(d+4) = o1;
  } else {
    float* d = featM + (size_t)r*DD + c;
    *(float4*)d     = make_float4(vb[0],vb[1],vb[2],vb[3]);
    *(float4*)(d+4) = make_float4(vb[4],vb[5],vb[6],vb[7]);
  }
}

// init: deg=0, tgt_of=-1, acc=0
__global__ __launch_bounds__(256) void k_init(
    int* __restrict__ degAll, int nDeg,
    int* __restrict__ tgt_of, int Nn,
    float* __restrict__ acc, int BT)
{
  int i = blockIdx.x*256 + threadIdx.x;
  if (i < nDeg) degAll[i] = 0;
  if (i < Nn) tgt_of[i] = -1;
  if (i < BT) acc[i] = 0.f;
}

// ---------------- merged CSR build (big + meta graphs) ----------------
__global__ __launch_bounds__(256) void k_hist2(
    const int* __restrict__ dstB, const int* __restrict__ dstM,
    int* __restrict__ degB, int* __restrict__ degM, int E, int ME, int nbE){
  int b = blockIdx.x, t = threadIdx.x;
  if (b < nbE){ int i = b*256+t; if (i < E) atomicAdd(&degB[dstB[i]], 1); }
  else { int i = (b-nbE)*256+t; if (i < ME) atomicAdd(&degM[dstM[i]], 1); }
}

__global__ __launch_bounds__(256) void k_scan1b(
    const int* __restrict__ degB, int* __restrict__ rpB, int* __restrict__ bsB,
    int nB, int nbB,
    const int* __restrict__ degM, int* __restrict__ rpM, int* __restrict__ bsM,
    int nM){
  __shared__ int ls[256];
  int blk = blockIdx.x, t = threadIdx.x;
  const int* deg; int* rowptr; int* bsum; int n; int b;
  if (blk < nbB){ deg=degB; rowptr=rpB; bsum=bsB; n=nB; b=blk; }
  else          { deg=degM; rowptr=rpM; bsum=bsM; n=nM; b=blk-nbB; }
  int base = b*1024 + t*4;
  int v0 = (base+0<n)?deg[base+0]:0;
  int v1 = (base+1<n)?deg[base+1]:0;
  int v2 = (base+2<n)?deg[base+2]:0;
  int v3 = (base+3<n)?deg[base+3]:0;
  int tsum = v0+v1+v2+v3;
  ls[t] = tsum; __syncthreads();
  for (int o=1;o<256;o<<=1){
    int x = (t>=o) ? ls[t-o] : 0;
    __syncthreads();
    ls[t] += x;
    __syncthreads();
  }
  int excl = ls[t]-tsum;
  if (t==255) bsum[b] = ls[255];
  if (base+0<n) rowptr[base+0]=excl;
  if (base+1<n) rowptr[base+1]=excl+v0;
  if (base+2<n) rowptr[base+2]=excl+v0+v1;
  if (base+3<n) rowptr[base+3]=excl+v0+v1+v2;
}

// scan3 with in-block prefix of block sums (scan2 merged in).
__global__ __launch_bounds__(256) void k_scan3b(
    int* __restrict__ rpB, const int* __restrict__ bsB, int* __restrict__ curB,
    int nB, int nb3B, int nbsB,
    int* __restrict__ rpM, const int* __restrict__ bsM, int* __restrict__ curM,
    int nM, int nbsM){
  __shared__ int spre;
  int blk = blockIdx.x, t = threadIdx.x;
  if (blk < nb3B){
    if (t == 0){
      int chunk = blk >> 2;
      int pre = 0;
      for (int j=0;j<chunk;j++) pre += bsB[j];
      spre = pre;
      if (blk == 0){
        int tot = 0;
        for (int j=0;j<nbsB;j++) tot += bsB[j];
        rpB[nB] = tot;
      }
    }
    __syncthreads();
    int i = blk*256 + t;
    if (i < nB){ int r = rpB[i] + spre; rpB[i] = r; curB[i] = r; }
  } else {
    int b2 = blk - nb3B;
    if (t == 0){
      int chunk = b2 >> 2;
      int pre = 0;
      for (int j=0;j<chunk;j++) pre += bsM[j];
      spre = pre;
      if (b2 == 0){
        int tot = 0;
        for (int j=0;j<nbsM;j++) tot += bsM[j];
        rpM[nM] = tot;
      }
    }
    __syncthreads();
    int i = b2*256 + t;
    if (i < nM){ int r = rpM[i] + spre; rpM[i] = r; curM[i] = r; }
  }
}

// scatter. Big graph: pack (src | meid<<17) into one int.
// Extra final block: target -> node chain (tgt_of/tgt_next) for fused readout.
__global__ __launch_bounds__(256) void k_scatter2(
    const int* __restrict__ dstB, const int* __restrict__ srcB,
    const int* __restrict__ auxB, int* __restrict__ curB,
    int* __restrict__ epackB, int E, int nbE,
    const int* __restrict__ dstM, const int* __restrict__ srcM,
    int* __restrict__ curM, int* __restrict__ esrcM, int* __restrict__ eauxM,
    int ME, int nbME,
    const int* __restrict__ tgt, int* __restrict__ tgt_of,
    int* __restrict__ tgt_next, int BT){
  int blk = blockIdx.x, t = threadIdx.x;
  if (blk < nbE){
    int e = blk*256 + t;
    if (e < E){
      int p = atomicAdd(&curB[dstB[e]], 1);
      epackB[p] = srcB[e] | (auxB[e] << 17);
    }
  } else if (blk < nbE + nbME){
    int e = (blk-nbE)*256 + t;
    if (e < ME){
      int p = atomicAdd(&curM[dstM[e]], 1);
      esrcM[p] = srcM[e];
      eauxM[p] = e;
    }
  } else {
    for (int i=t; i<BT; i+=256){
      int old = atomicExch(&tgt_of[tgt[i]], i);
      tgt_next[i] = old;
    }
  }
}

// ---------------- meta-graph edges: CSR, atomic-free, writes mef ----------------
// agg written PRE-NORMALIZED (softmax denominator folded in here).
__global__ __launch_bounds__(256) void edge_meta_csr(
    const int* __restrict__ rowptr, const int* __restrict__ esrc,
    const int* __restrict__ eorig,
    const unsigned short* __restrict__ qm, const unsigned short* __restrict__ kfm,
    const unsigned short* __restrict__ vm,
    const float* __restrict__ base, unsigned short* __restrict__ mef,
    float* __restrict__ agg, int NM)
{
  int d = blockIdx.x*4 + (threadIdx.x>>6);
  if (d >= NM) return;
  int lane = threadIdx.x & 63;
  const float* be2 = base+152; const float* be1 = base+16; const float* bn1 = base+8;
  size_t dq = (size_t)d*DD;
  float q0 = b2f(qm[dq+lane]), q1 = b2f(qm[dq+64+lane]);
  float w0 = be2[lane], w1 = be2[64+lane];
  int h0 = lane>>4, h1 = h0+4;
  float bias0 = be1[h0] + bn1[h0];
  float bias1 = be1[h1] + bn1[h1];
  float z0=0.f, z1=0.f, a0=0.f, a1=0.f;
  int i0 = rowptr[d], i1 = rowptr[d+1];
  for (int i=i0; i<i1; i++){
    int s = esrc[i], e = eorig[i];
    size_t so=(size_t)s*DD, eo=(size_t)e*DD;
    float ke0 = b2f(kfm[so+lane])    * w0;
    float ke1 = b2f(kfm[so+64+lane]) * w1;
    mef[eo+lane]=f2b(ke0); mef[eo+64+lane]=f2b(ke1);
    float p0 = q0*ke0, p1 = q1*ke1;
#pragma unroll
    for (int m=1;m<16;m<<=1){ p0 += __shfl_xor(p0,m,64); p1 += __shfl_xor(p1,m,64); }
    float e0 = __expf(p0*0.25f + bias0);
    float e1 = __expf(p1*0.25f + bias1);
    z0 += e0; z1 += e1;
    a0 += e0*b2f(vm[so+lane]);
    a1 += e1*b2f(vm[so+64+lane]);
  }
  float inv0 = 1.f/(z0 + 1e-9f);
  float inv1 = 1.f/(z1 + 1e-9f);
  agg[dq+lane]    = a0*inv0;
  agg[dq+64+lane] = a1*inv1;
}

// Fused meta-learner over [meta_out (Ma rows, f32) | mef (bf16)].
// 4 rows per block; u/W2/W1 columns cached in registers across rows.
__global__ __launch_bounds__(128) void learner2(
    const float* __restrict__ Xa, const unsigned short* __restrict__ Xb,
    int Ma, int Mtot,
    const void* __restrict__ u, const void* __restrict__ W2,
    const void* __restrict__ W1,
    float* __restrict__ p2a, float* __restrict__ p1a,
    unsigned short* __restrict__ w2me, unsigned short* __restrict__ p1b,
    const float* __restrict__ base, const int* __restrict__ dflag)
{
  __shared__ float sX[128];
  __shared__ float st[16];
  __shared__ float sw[16];
  const bool wf32 = (*dflag) != 0;
  const int t = threadIdx.x;
  const int l = t>>3, j = t&7;
  float uc[16], w2c[16], w1c[16];
#pragma unroll
  for (int m=0;m<16;m++) uc[m] = gld(u, (size_t)l*128 + j*16 + m, wf32);
#pragma unroll
  for (int i=0;i<16;i++) w2c[i] = gld(W2, (size_t)i*128 + t, wf32);
  if (t < 8){
#pragma unroll
    for (int i=0;i<16;i++) w1c[i] = gld(W1, (size_t)i*8 + t, wf32);
  }
  for (int rr=0; rr<4; rr++){
    int row = blockIdx.x*4 + rr;
    if (row >= Mtot) break;
    const bool isB = (row >= Ma);
    const int m = isB ? (row - Ma) : row;
    if (isB) sX[t] = b2f(Xb[(size_t)m*DD + t]);
    else     sX[t] = Xa[(size_t)m*DD + t];
    __syncthreads();
    float part = 0.f;
#pragma unroll
    for (int mm=0;mm<16;mm++) part += sX[j*16+mm]*uc[mm];
    part += __shfl_xor(part,1,64); part += __shfl_xor(part,2,64); part += __shfl_xor(part,4,64);
    if (j==0) st[l] = part * 0.08838834764831845f;
    __syncthreads();
    float mx=-1e30f;
    for (int i=0;i<16;i++) mx = fmaxf(mx, st[i]);
    float ssum=0.f;
    for (int i=0;i<16;i++) ssum += __expf(st[i]-mx);
    float inv = 1.f/ssum;
    if (t<16) sw[t] = __expf(st[t]-mx)*inv;
    __syncthreads();
    float a=0.f;
#pragma unroll
    for (int i=0;i<16;i++) a += sw[i]*w2c[i];
    if (isB) w2me[(size_t)m*DD+t] = f2b(base[152+t] + a);
    else     p2a[(size_t)m*DD+t] = a;
    if (t<8){
      float bb=0.f;
#pragma unroll
      for (int i=0;i<16;i++) bb += sw[i]*w1c[i];
      if (isB) p1b[(size_t)m*HH+t] = f2b(bb);
      else     p1a[(size_t)m*HH+t] = bb;
    }
    __syncthreads();
  }
}

// ---------------- big-graph: fused scores+agg, fp8 kv, packed indices ----------
// R2/R4 hybrid (best measured): one 16-lane group per dst node, natural order,
// node-major 256B kv rows fully consumed; q head-scale (base_n2 + p2mn[mnid])
// applied IN-KERNEL (cheaper than a separate q gemm: R4 571.9 vs R8 594.2).
// agg PRE-NORMALIZED (0.125 fp8 v-descale folded into 1/z).
__global__ __launch_bounds__(256) void edge_fused(
    const int* __restrict__ rowptr, const int* __restrict__ epack,
    const int* __restrict__ mnid,
    const unsigned short* __restrict__ q, const unsigned char* __restrict__ kv8,
    const unsigned short* __restrict__ w2me, const unsigned short* __restrict__ p1me,
    const float* __restrict__ p1mn, const float* __restrict__ p2mn,
    const float* __restrict__ base,
    unsigned short* __restrict__ aggb, int N)
{
  int wv = blockIdx.x*4 + (threadIdx.x>>6);
  int lane = threadIdx.x & 63;
  int grp = lane >> 4, l16 = lane & 15;
  int d = wv*4 + grp;                 // each 16-lane group owns one dst node
  if (d >= N) return;
  int c8 = l16 * 8;
  int h = l16 >> 1;

  int i0 = rowptr[d], i1 = rowptr[d+1];
  int mn = mnid[d];
  float bias = base[16+h] + base[8+h] + p1mn[(size_t)mn*HH + h];
  size_t dq = (size_t)d*DD;
  float qv[8];
  {
    uint4 qraw = *(const uint4*)(q + dq + c8);
    const unsigned short* qh = (const unsigned short*)&qraw;
    const float* p2 = p2mn + (size_t)mn*DD + c8;
    const float* sv = base + 24 + c8;       // base_n2
#pragma unroll
    for (int j=0;j<8;j++) qv[j] = b2f(qh[j]) * (sv[j] + p2[j]) * 0.03125f; // 0.25/8
  }

  float zh = 0.f;
  float a[8];
#pragma unroll
  for (int j=0;j<8;j++) a[j] = 0.f;

  int i = i0;
  for (; i + 1 < i1; i += 2){
    unsigned int v0p = (unsigned int)epack[i];
    unsigned int v1p = (unsigned int)epack[i+1];
    int s0 = v0p & 0x1FFFF, me0 = v0p >> 17;
    int s1 = v1p & 0x1FFFF, me1 = v1p >> 17;
    const unsigned char* kv0 = kv8 + (size_t)s0*256 + c8;
    const unsigned char* kv1 = kv8 + (size_t)s1*256 + c8;
    uint2 kraw0 = *(const uint2*)kv0;
    uint2 vraw0 = *(const uint2*)(kv0 + 128);
    uint4 wraw0 = *(const uint4*)(w2me + (size_t)me0*DD + c8);
    float pm0 = b2f(p1me[(size_t)me0*HH + h]);
    uint2 kraw1 = *(const uint2*)kv1;
    uint2 vraw1 = *(const uint2*)(kv1 + 128);
    uint4 wraw1 = *(const uint4*)(w2me + (size_t)me1*DD + c8);
    float pm1 = b2f(p1me[(size_t)me1*HH + h]);
    float k0f[8], v0f[8], k1f[8], v1f[8];
    cvt4(kraw0.x, k0f); cvt4(kraw0.y, k0f+4);
    cvt4(vraw0.x, v0f); cvt4(vraw0.y, v0f+4);
    cvt4(kraw1.x, k1f); cvt4(kraw1.y, k1f+4);
    cvt4(vraw1.x, v1f); cvt4(vraw1.y, v1f+4);
    const unsigned short* wh0 = (const unsigned short*)&wraw0;
    const unsigned short* wh1 = (const unsigned short*)&wraw1;
    float pA = 0.f, pB = 0.f;
#pragma unroll
    for (int j=0;j<8;j++){
      pA += qv[j]*(k0f[j]*b2f(wh0[j]));
      pB += qv[j]*(k1f[j]*b2f(wh1[j]));
    }
    pA += __shfl_xor(pA, 1, 64);
    pB += __shfl_xor(pB, 1, 64);
    float ex0 = __expf(pA + bias + pm0);
    float ex1 = __expf(pB + bias + pm1);
    zh += ex0 + ex1;
#pragma unroll
    for (int j=0;j<8;j++) a[j] += ex0*v0f[j] + ex1*v1f[j];
  }
  if (i < i1){
    unsigned int vp = (unsigned int)epack[i];
    int s = vp & 0x1FFFF, me = vp >> 17;
    const unsigned char* kv = kv8 + (size_t)s*256 + c8;
    uint2 kraw = *(const uint2*)kv;
    uint2 vraw = *(const uint2*)(kv + 128);
    uint4 wraw = *(const uint4*)(w2me + (size_t)me*DD + c8);
    float pm = b2f(p1me[(size_t)me*HH + h]);
    float kf[8], vf[8];
    cvt4(kraw.x, kf); cvt4(kraw.y, kf+4);
    cvt4(vraw.x, vf); cvt4(vraw.y, vf+4);
    const unsigned short* wh = (const unsigned short*)&wraw;
    float p = 0.f;
#pragma unroll
    for (int j=0;j<8;j++) p += qv[j]*(kf[j]*b2f(wh[j]));
    p += __shfl_xor(p, 1, 64);
    float ex = __expf(p + bias + pm);
    zh += ex;
#pragma unroll
    for (int j=0;j<8;j++) a[j] += ex*vf[j];
  }

  // each lane owns its 8 channels; zh is per-head (same in both pair lanes)
  float inv = 0.125f / (zh + 1e-9f);   // fp8 v-descale folded into 1/z
  us8 o;
#pragma unroll
  for (int j=0;j<8;j++) o.s[j] = f2b(a[j]*inv);
  *(us8*)(aggb + dq + c8) = o;
}

// final: out = acc * invNB (readout accumulated in gemm128m epilogues)
__global__ __launch_bounds__(256) void k_finish(
    const float* __restrict__ acc, void* __restrict__ out,
    float invNB, int BT, const int* __restrict__ dflag)
{
  int t = blockIdx.x*256 + threadIdx.x;
  if (t >= BT) return;
  float r = acc[t] * invNB;
  if ((*dflag) != 0) ((float*)out)[t] = r;
  else ((__hip_bfloat16*)out)[t] = __float2bfloat16(r);
}

extern "C" void kernel_launch(void* const* d_in, const int* in_sizes, int n_in,
                              void* d_out, int out_size, void* d_ws, size_t ws_size,
                              hipStream_t stream) {
  const void* emb   = d_in[0];
  const void* u     = d_in[1];
  const void* W2lat = d_in[2];
  const void* W1lat = d_in[3];
  WPtrs wptrs;
  for (int i=0;i<8;i++) wptrs.p[i] = d_in[4+i];
  const int* node_vals      = (const int*)d_in[12];
  const int* meta_node_vals = (const int*)d_in[13];
  const int* src            = (const int*)d_in[14];
  const int* dst            = (const int*)d_in[15];
  const int* meta_src       = (const int*)d_in[16];
  const int* meta_dst       = (const int*)d_in[17];
  const int* meta_node_id   = (const int*)d_in[18];
  const int* meta_edge_id   = (const int*)d_in[19];
  const int* target_idx     = (const int*)d_in[20];
  const int* static_vals    = (const int*)d_in[21];
  const int* static_src     = (const int*)d_in[22];
  const int* static_dst     = (const int*)d_in[23];

  const int N  = in_sizes[12];
  const int MN = in_sizes[13];
  const int E  = in_sizes[14];
  const int ME = in_sizes[16];
  const int BT = in_sizes[20];
  const int NSRC = in_sizes[22];
  const int NB = in_sizes[8] / (DD*DD);

  float* ws = (float*)d_ws;
  size_t off = 0;
  // keep every allocation 16B-aligned (global_load_lds sources need it)
  auto allocf = [&](size_t n){ float* p = ws + off; off += (n + 3) & ~(size_t)3; return p; };
  auto allocb = [&](size_t n){ unsigned short* p = (unsigned short*)(ws + off); off += (((n+1)/2) + 3) & ~(size_t)3; return p; };
  auto alloci = [&](size_t n){ int* p = (int*)(ws + off); off += (n + 3) & ~(size_t)3; return p; };
  int*            dflag = (int*)ws; off += 4;
  unsigned short* feat  = allocb((size_t)N*DD);
  unsigned short* q     = allocb((size_t)N*DD);
  unsigned char*  kv8   = (unsigned char*)allocf((size_t)N*64);  // N x 256B fp8 rows
  unsigned short* aggb  = allocb((size_t)N*DD);
  float*          meta_feat= allocf((size_t)MN*DD);
  float*          agg_m = allocf((size_t)MN*DD);
  unsigned short* q_m   = allocb((size_t)MN*DD);
  unsigned short* kf_m  = allocb((size_t)MN*DD);
  unsigned short* v_m   = allocb((size_t)MN*DD);
  float*          meta_out = allocf((size_t)MN*DD);
  unsigned short* mef   = allocb((size_t)ME*DD);
  float*          p2mn  = allocf((size_t)MN*DD);
  float*          p1mn  = allocf((size_t)MN*HH);
  unsigned short* w2me  = allocb((size_t)ME*DD);
  unsigned short* p1me  = allocb((size_t)ME*HH);
  float*          base  = allocf(280);
  float*          acc   = allocf((size_t)BT);
  unsigned short* wstage= allocb((size_t)8*NB*DD*DD);
  int*            rowptr= alloci((size_t)N+1);
  int*            cursor= alloci((size_t)N);
  int*            epack = alloci((size_t)E);
  int*            rowptr_m= alloci((size_t)MN+1);
  int*            cursor_m= alloci((size_t)MN);
  int*            esrc_m  = alloci((size_t)ME);
  int*            eorig_m = alloci((size_t)ME);
  int*            degAll  = alloci((size_t)(N+MN));
  int*            deg     = degAll;
  int*            deg_m   = degAll + N;
  int*            tgt_of  = alloci((size_t)N);
  int*            tgt_next= alloci((size_t)BT);
  const int nb_scan   = (N + 1023)/1024;
  const int nb_scan_m = (MN + 1023)/1024;
  int*            bsum   = alloci((size_t)nb_scan);
  int*            bsum_m = alloci((size_t)nb_scan_m);
  (void)ws_size; (void)n_in; (void)out_size;

  const float* base_n2 = base + 24;

  k_init<<<(N+MN+255)/256,256,0,stream>>>(degAll, N+MN, tgt_of, N, acc, BT);
  k_static<<<1,256,0,stream>>>(emb, static_vals, static_src, static_dst,
                               u, W2lat, W1lat, base, NSRC, dflag);
  const int gB = ((N+MN)*16+255)/256;
  gather_repack<<<gB + 8*NB*64,256,0,stream>>>(emb, node_vals, feat, N,
      meta_node_vals, meta_feat, MN, wptrs, wstage, NB, dflag, gB);

  const int nbE  = (E+255)/256, nbME = (ME+255)/256;
  const int nb3B = (N+255)/256, nb3M = (MN+255)/256;
  k_hist2<<<nbE+nbME,256,0,stream>>>(dst, meta_dst, deg, deg_m, E, ME, nbE);
  k_scan1b<<<nb_scan+nb_scan_m,256,0,stream>>>(deg, rowptr, bsum, N, nb_scan,
      deg_m, rowptr_m, bsum_m, MN);
  k_scan3b<<<nb3B+nb3M,256,0,stream>>>(rowptr, bsum, cursor, N, nb3B, nb_scan,
      rowptr_m, bsum_m, cursor_m, MN, nb_scan_m);
  k_scatter2<<<nbE+nbME+1,256,0,stream>>>(dst, src, meta_edge_id, cursor,
      epack, E, nbE, meta_dst, meta_src, cursor_m, esrc_m, eorig_m, ME, nbME,
      target_idx, tgt_of, tgt_next, BT);

  const int gm = (MN+63)/64;
  const int gN = (N+63)/64;
  const float invNB = 1.0f/(float)NB;

  for (int b=0;b<NB;b++){
    const unsigned short* wq_m = wstage + (size_t)(0*NB+b)*DD*DD;
    const unsigned short* wk_m = wstage + (size_t)(1*NB+b)*DD*DD;
    const unsigned short* wv_m = wstage + (size_t)(2*NB+b)*DD*DD;
    const unsigned short* wo_m = wstage + (size_t)(3*NB+b)*DD*DD;
    const unsigned short* wqb  = wstage + (size_t)(4*NB+b)*DD*DD;
    const unsigned short* wkb  = wstage + (size_t)(5*NB+b)*DD*DD;
    const unsigned short* wvb  = wstage + (size_t)(6*NB+b)*DD*DD;
    const unsigned short* wob  = wstage + (size_t)(7*NB+b)*DD*DD;

    // ---- merged big+meta QKV (big q plain; scale deferred to edge_fused) ----
    gemm_qkv2<<<gN+gm,256,0,stream>>>(feat, meta_feat,
        wqb, wkb, wvb, wq_m, wk_m, wv_m,
        q, kv8, q_m, kf_m, v_m, N, MN, gN, base_n2);

    // ---- meta conv (CSR, atomic-free) ----
    edge_meta_csr<<<(MN+3)/4,256,0,stream>>>(rowptr_m, esrc_m, eorig_m,
        q_m, kf_m, v_m, base, mef, agg_m, MN);
    // meta Wo: meta_out = relu(agg_m@Wo) (f32, agg pre-normalized); meta_feat += relu
    gemm128m<EPI_RELU_RES2,false,false><<<gm,256,0,stream>>>(agg_m, wo_m,
        meta_out, MN, nullptr, meta_feat, meta_feat,
        nullptr, nullptr, nullptr, nullptr, nullptr, nullptr);
    // wide fused learners: MN rows (f32 meta_out) + ME rows (bf16 mef)
    learner2<<<(MN+ME+3)/4,128,0,stream>>>(meta_out, mef, MN, MN+ME,
        u, W2lat, W1lat, p2mn, p1mn, w2me, p1me, base, dflag);

    // ---- big conv (in-kernel q head-scale; minimal-bytes kv layout) ----
    edge_fused<<<(N+15)/16,256,0,stream>>>(rowptr, epack,
        meta_node_id, q, kv8, w2me, p1me, p1mn, p2mn, base, aggb, N);
    // big Wo + residual + FUSED READOUT into acc
    gemm128m<EPI_RELU_RES,true,true><<<gN,256,0,stream>>>(aggb, wob, feat, N,
        feat, nullptr, nullptr,
        meta_node_id, p1mn, base, tgt_of, tgt_next, acc);
  }
  k_finish<<<(BT+255)/256,256,0,stream>>>(acc, d_out, invNB, BT, dflag);
}

// Round 10
// 545.004 us; speedup vs baseline: 1.4128x; 1.0177x over previous
//
#include <hip/hip_runtime.h>
#include <hip/hip_bf16.h>
#include <hip/hip_fp8.h>

#define DD   128
#define HH   8

typedef short bf16x8 __attribute__((ext_vector_type(8)));
typedef float f32x4  __attribute__((ext_vector_type(4)));
typedef float f32x2  __attribute__((ext_vector_type(2)));

__device__ __forceinline__ float b2f(unsigned short v){
  union { unsigned int u; float f; } x; x.u = ((unsigned int)v) << 16; return x.f;
}
__device__ __forceinline__ unsigned short f2b(float f){
  __hip_bfloat16 h = __float2bfloat16(f);
  return *(unsigned short*)&h;
}
__device__ __forceinline__ unsigned char f2f8(float x){
  __hip_fp8_e4m3 h(x);
  return h.__x;
}
__device__ __forceinline__ float f82f(unsigned char b){
  __hip_fp8_e4m3 h; h.__x = b;
  return (float)h;
}
// 4 fp8 bytes (one u32) -> 4 floats; HW packed cvt when available.
__device__ __forceinline__ void cvt4(unsigned int w, float* o){
#if defined(__has_builtin)
# if __has_builtin(__builtin_amdgcn_cvt_pk_f32_fp8)
  f32x2 lo = __builtin_amdgcn_cvt_pk_f32_fp8((int)w, false);
  f32x2 hi = __builtin_amdgcn_cvt_pk_f32_fp8((int)w, true);
  o[0]=lo[0]; o[1]=lo[1]; o[2]=hi[0]; o[3]=hi[1];
  return;
# endif
#endif
  o[0]=f82f(w&0xff); o[1]=f82f((w>>8)&0xff);
  o[2]=f82f((w>>16)&0xff); o[3]=f82f((w>>24)&0xff);
}
struct __align__(8) us4 { unsigned short x,y,z,w; };
struct __align__(16) us8 { unsigned short s[8]; };

__device__ __forceinline__ float gld(const void* p, size_t i, bool f32){
  if (f32) return ((const float*)p)[i];
  return b2f(((const unsigned short*)p)[i]);
}

// async global->LDS, 16B per lane (wave-uniform LDS base + lane*16)
__device__ __forceinline__ void gll16(const void* g, void* l){
  __builtin_amdgcn_global_load_lds(
      (const __attribute__((address_space(1))) unsigned int*)g,
      (__attribute__((address_space(3))) unsigned int*)l, 16, 0, 0);
}

struct WPtrs { const void* p[8]; };

#define CPAD 132

// C[M,128] = relu( A[M,128] @ B[128,128] ) + Rb, bf16 out. B TRANSPOSED [n][k].
// FUSED READOUT: target rows (tgt_of chain) accumulate tw.feat into acc[ti].
__global__ __launch_bounds__(256) void gemm_wo(
    const void* __restrict__ Av, const unsigned short* __restrict__ Bt,
    void* __restrict__ Cv, int M,
    const unsigned short* __restrict__ Rb,
    const int* __restrict__ mnid, const float* __restrict__ p1mn,
    const float* __restrict__ base,
    const int* __restrict__ tgt_of, const int* __restrict__ tgt_next,
    float* __restrict__ acc)
{
  __shared__ __align__(16) unsigned short Asb[64*128];
  __shared__ __align__(16) unsigned short Btb[16896];  // B: 32KB / C: 64x132 f32
  const int tid = threadIdx.x;
  const int wave = tid >> 6, lane = tid & 63;
  const int row0 = blockIdx.x * 64;

  {
    const char* Ab = (const char*)Av;
    int n4 = lane >> 4, c = lane & 15;
#pragma unroll
    for (int op=0; op<4; op++){
      int rA = wave*16 + op*4;
      int n = rA + n4;
      int gr = row0 + n; if (gr >= M) gr = M - 1;
      gll16(Ab + (size_t)gr*256 + ((size_t)((c ^ (n & 7)) << 4)), &Asb[rA*128]);
    }
  }
  {
    int n4 = lane >> 4, c = lane & 15;
#pragma unroll
    for (int op=0; op<8; op++){
      int rB = wave*32 + op*4;
      int n = rB + n4;
      gll16((const char*)Bt + (size_t)n*256 + ((size_t)((c ^ (n & 7)) << 4)),
            &Btb[rB*128]);
    }
  }
  __syncthreads();

  f32x4 acc0[8];
#pragma unroll
  for (int t=0;t<8;t++) acc0[t] = (f32x4){0.f,0.f,0.f,0.f};
  const int am = (lane & 15), kq = (lane >> 4) * 8, axr = (am & 7) << 3;
#pragma unroll
  for (int k0=0;k0<128;k0+=32){
    int xo = (k0 + kq) ^ axr;
    bf16x8 a = *(bf16x8*)&Asb[(wave*16 + am)*128 + xo];
#pragma unroll
    for (int t=0;t<8;t++){
      bf16x8 b = *(bf16x8*)&Btb[(t*16 + am)*128 + xo];
      acc0[t] = __builtin_amdgcn_mfma_f32_16x16x32_bf16(a, b, acc0[t], 0,0,0);
    }
  }
  __syncthreads();
  float* Cls = (float*)Btb;
  {
    int rr = wave*16 + (lane>>4)*4;
    int cc = lane & 15;
#pragma unroll
    for (int t=0;t<8;t++)
#pragma unroll
      for (int r=0;r<4;r++)
        Cls[(rr + r)*CPAD + t*16 + cc] = acc0[t][r];
  }
  __syncthreads();

  {
    int r = tid >> 2, cb = (tid & 3) * 32;
    int gr = row0 + r;
    if (gr < M){
      float hs0 = 0.f, hs1 = 0.f;
#pragma unroll
      for (int j=0;j<8;j++){
        int c = cb + j*4;
        float4 o = *(float4*)&Cls[r*CPAD + c];
        us4 rb = *(const us4*)(Rb + (size_t)gr*DD + c);
        o.x=fmaxf(o.x,0.f)+b2f(rb.x); o.y=fmaxf(o.y,0.f)+b2f(rb.y);
        o.z=fmaxf(o.z,0.f)+b2f(rb.z); o.w=fmaxf(o.w,0.f)+b2f(rb.w);
        float s4 = o.x + o.y + o.z + o.w;
        if (j < 4) hs0 += s4; else hs1 += s4;
        us4 ob; ob.x=f2b(o.x); ob.y=f2b(o.y); ob.z=f2b(o.z); ob.w=f2b(o.w);
        *(us4*)((unsigned short*)Cv + (size_t)gr*DD + c) = ob;
      }
      // fused readout: logit partial for this row's 2 heads, reduce 4 lanes,
      // push to acc for each target pointing at this node (chain, rare).
      int hb = cb >> 4;
      int mn = mnid[gr];
      float tw0 = base[hb]     + p1mn[(size_t)mn*HH + hb];
      float tw1 = base[hb + 1] + p1mn[(size_t)mn*HH + hb + 1];
      float part = tw0*hs0 + tw1*hs1;
      part += __shfl_xor(part, 1, 64);
      part += __shfl_xor(part, 2, 64);
      if ((tid & 3) == 0){
        int ti = tgt_of[gr];
        while (ti >= 0){
          atomicAdd(&acc[ti], part);
          ti = tgt_next[ti];
        }
      }
    }
  }
}

enum { EPI_STORE=0, EPI_SCALE_CONST=1 };

// Fused Q/K/V gemm body. FP8KV (big): ph0 -> q bf16 node-major (plain store,
// head scale deferred to edge_fused); ph1/2 -> fp8 (x8) into 256B/row kv buf.
// !FP8KV (meta): 3 phases node-major bf16, q scaled by svec.
template<int EPIQ, bool INB, bool FP8KV>
__device__ __forceinline__ void qkv_body(
    unsigned short* Asb, unsigned short* Btb, int blk,
    const void* __restrict__ Av,
    const unsigned short* __restrict__ Btq, const unsigned short* __restrict__ Btk,
    const unsigned short* __restrict__ Btv,
    void* __restrict__ Cq, void* __restrict__ Ck, int stK,
    void* __restrict__ Cvo, int stV, int M,
    const float* __restrict__ svec)
{
  const int tid = threadIdx.x;
  const int wave = tid >> 6, lane = tid & 63;
  const int row0 = blk * 64;

  if (INB){
    const char* Ab = (const char*)Av;
    int n4 = lane >> 4, c = lane & 15;
#pragma unroll
    for (int op=0; op<4; op++){
      int rA = wave*16 + op*4;
      int n = rA + n4;
      int gr = row0 + n; if (gr >= M) gr = M - 1;
      gll16(Ab + (size_t)gr*256 + ((size_t)((c ^ (n & 7)) << 4)), &Asb[rA*128]);
    }
  } else {
    const float* Af = (const float*)Av;
    int r = tid >> 2, cb = (tid & 3) * 32, rx = (r & 7) << 3;
    int gr = row0 + r;
#pragma unroll
    for (int j=0;j<8;j++){
      int cc = cb + j*4;
      float4 val = make_float4(0.f,0.f,0.f,0.f);
      if (gr < M) val = *(const float4*)(Af + (size_t)gr*DD + cc);
      us4 o; o.x=f2b(val.x); o.y=f2b(val.y); o.z=f2b(val.z); o.w=f2b(val.w);
      *(us4*)&Asb[r*128 + (cc ^ rx)] = o;
    }
  }

  const unsigned short* Bts[3] = {Btq, Btk, Btv};
  void* Cs[3] = {Cq, Ck, Cvo};
  const int sts[3] = {DD, stK, stV};
  const int am = (lane & 15), kq = (lane >> 4) * 8, axr = (am & 7) << 3;

  for (int ph=0; ph<3; ph++){
    {
      const unsigned short* Bt = Bts[ph];
      int n4 = lane >> 4, c = lane & 15;
#pragma unroll
      for (int op=0; op<8; op++){
        int rB = wave*32 + op*4;
        int n = rB + n4;
        gll16((const char*)Bt + (size_t)n*256 + ((size_t)((c ^ (n & 7)) << 4)),
              &Btb[rB*128]);
      }
    }
    __syncthreads();
    f32x4 acc[8];
#pragma unroll
    for (int t=0;t<8;t++) acc[t] = (f32x4){0.f,0.f,0.f,0.f};
#pragma unroll
    for (int k0=0;k0<128;k0+=32){
      int xo = (k0 + kq) ^ axr;
      bf16x8 a = *(bf16x8*)&Asb[(wave*16 + am)*128 + xo];
#pragma unroll
      for (int t=0;t<8;t++){
        bf16x8 b = *(bf16x8*)&Btb[(t*16 + am)*128 + xo];
        acc[t] = __builtin_amdgcn_mfma_f32_16x16x32_bf16(a, b, acc[t], 0,0,0);
      }
    }
    __syncthreads();
    float* Cls = (float*)Btb;
    {
      int rr = wave*16 + (lane>>4)*4;
      int cc = lane & 15;
#pragma unroll
      for (int t=0;t<8;t++)
#pragma unroll
        for (int r=0;r<4;r++)
          Cls[(rr + r)*CPAD + t*16 + cc] = acc[t][r];
    }
    __syncthreads();
    {
      int r = tid >> 2, cb = (tid & 3) * 32;
      int gr = row0 + r;
      if (gr < M){
#pragma unroll
        for (int j=0;j<8;j++){
          int c = cb + j*4;
          float4 o = *(float4*)&Cls[r*CPAD + c];
          if (ph == 0 && EPIQ == EPI_SCALE_CONST){
            o.x*=svec[c+0]; o.y*=svec[c+1]; o.z*=svec[c+2]; o.w*=svec[c+3];
          }
          if (FP8KV && ph > 0){
            unsigned char* Cb = (unsigned char*)Cs[ph];
            uchar4 ob;
            ob.x=f2f8(o.x*8.f); ob.y=f2f8(o.y*8.f);
            ob.z=f2f8(o.z*8.f); ob.w=f2f8(o.w*8.f);
            *(uchar4*)(Cb + (size_t)gr*256 + c) = ob;
          } else {
            us4 ob; ob.x=f2b(o.x); ob.y=f2b(o.y); ob.z=f2b(o.z); ob.w=f2b(o.w);
            *(us4*)((unsigned short*)Cs[ph] + (size_t)gr*sts[ph] + c) = ob;
          }
        }
      }
    }
    __syncthreads();
  }
}

// Merged big+meta QKV in one dispatch: blocks [0,gN) big graph (bf16 in,
// plain q + fp8 kv out); blocks [gN, gN+gm) meta graph (f32 in, scaled q).
__global__ __launch_bounds__(256) void gemm_qkv2(
    const unsigned short* __restrict__ featB, const float* __restrict__ featM,
    const unsigned short* __restrict__ wqb, const unsigned short* __restrict__ wkb,
    const unsigned short* __restrict__ wvb,
    const unsigned short* __restrict__ wqm, const unsigned short* __restrict__ wkm,
    const unsigned short* __restrict__ wvm,
    unsigned short* __restrict__ qB, unsigned char* __restrict__ kv8,
    unsigned short* __restrict__ qM, unsigned short* __restrict__ kfM,
    unsigned short* __restrict__ vM,
    int Nbig, int Nmeta, int gN, const float* __restrict__ svec)
{
  __shared__ __align__(16) unsigned short Asb[64*128];
  __shared__ __align__(16) unsigned short Btb[16896];
  if (blockIdx.x < gN){
    qkv_body<EPI_STORE,true,true>(Asb, Btb, blockIdx.x, featB,
        wqb, wkb, wvb, qB, kv8, 0, kv8 + 128, 0, Nbig, svec);
  } else {
    qkv_body<EPI_SCALE_CONST,false,false>(Asb, Btb, blockIdx.x - gN, featM,
        wqm, wkm, wvm, qM, kfM, DD, vM, DD, Nmeta, svec);
  }
}

// ============ merged setup: static params + init + gather + repack ==========
// blk 0: static param-name graph -> base (+ dflag).  blks [1,1+nInit): init.
// remaining: gather rows / weight repack (per-block dtype flag recompute —
// 128 ushort L2-broadcast read, free).
__global__ __launch_bounds__(256) void k_setup(
    const void* __restrict__ emb, const int* __restrict__ svals,
    const int* __restrict__ ssrc, const int* __restrict__ sdst,
    const void* __restrict__ u, const void* __restrict__ W2,
    const void* __restrict__ W1, float* __restrict__ base, int nsrc,
    int* __restrict__ dflag,
    int* __restrict__ degAll, int nDeg, int* __restrict__ tgt_of, int Nn,
    float* __restrict__ acc, int BT,
    const int* __restrict__ valsB, unsigned short* __restrict__ featB, int nB,
    const int* __restrict__ valsM, float* __restrict__ featM, int nM,
    WPtrs W, unsigned short* __restrict__ stage, int NBt,
    int nInit, int gB)
{
  const int t = threadIdx.x;
  int blk = blockIdx.x;
  if (blk == 0){
    __shared__ float sagg[15][128];
    __shared__ float ssc[15][16];
    __shared__ float sww[15][16];
    __shared__ int swf0;
    if (t < 64){
      float m = 0.f;
      for (int i=t; i<128; i+=64){
        float x = fabsf(b2f(((const unsigned short*)emb)[i]));
        if (x < 1e30f) m = fmaxf(m, x);
      }
#pragma unroll
      for (int s=1;s<64;s<<=1) m = fmaxf(m, __shfl_xor(m, s, 64));
      if (t==0){ int f = (m > 1e4f) ? 1 : 0; *dflag = f; swf0 = f; }
    }
    for (int i=t;i<15*128;i+=256) ((float*)sagg)[i]=0.f;
    __syncthreads();
    const bool wf32 = (swf0 != 0);
    if (t < 128){
      for (int i=0;i<nsrc;i++){
        int row = sdst[i]; int vr = svals[ssrc[i]];
        sagg[row][t] += gld(emb, (size_t)vr*DD + t, wf32);
      }
    }
    __syncthreads();
    if (t < 240){
      int n = t>>4, l = t&15;
      float a=0.f;
      for (int d=0;d<128;d++) a += sagg[n][d]*gld(u, l*128+d, wf32);
      ssc[n][l] = a * 0.08838834764831845f;
    }
    __syncthreads();
    if (t < 15){
      float mx=-1e30f;
      for (int l=0;l<16;l++) mx = fmaxf(mx, ssc[t][l]);
      float s=0.f;
      for (int l=0;l<16;l++){ float e=__expf(ssc[t][l]-mx); sww[t][l]=e; s+=e; }
      float inv = 1.f/s;
      for (int l=0;l<16;l++) sww[t][l]*=inv;
    }
    __syncthreads();
    if (t < 8){
      float a=0.f,b=0.f,c=0.f;
      for (int l=0;l<16;l++){
        float wv = gld(W1, l*8+t, wf32);
        a += sww[0][l]*wv; b += sww[3][l]*wv; c += sww[9][l]*wv;
      }
      base[t]=a; base[8+t]=b; base[16+t]=c;
    }
    if (t < 128){
      float a=0.f,b=0.f;
      for (int l=0;l<16;l++){
        float wv = gld(W2, l*128+t, wf32);
        a += sww[6][l]*wv; b += sww[12][l]*wv;
      }
      base[24+t]=a; base[152+t]=b;
    }
    return;
  }
  blk -= 1;
  if (blk < nInit){
    int i = blk*256 + t;
    if (i < nDeg) degAll[i] = 0;
    if (i < Nn) tgt_of[i] = -1;
    if (i < BT) acc[i] = 0.f;
    return;
  }
  blk -= nInit;
  __shared__ int swf;
  if (t < 64){
    float m = 0.f;
    for (int i=t; i<128; i+=64){
      float x = fabsf(b2f(((const unsigned short*)emb)[i]));
      if (x < 1e30f) m = fmaxf(m, x);
    }
#pragma unroll
    for (int s=1;s<64;s<<=1) m = fmaxf(m, __shfl_xor(m, s, 64));
    if (t==0) swf = (m > 1e4f) ? 1 : 0;
  }
  __syncthreads();
  const bool wf32 = (swf != 0);
  if (blk >= gB){
    int bid = blk - gB;
    int idx = bid >> 6;
    int ti = idx / NBt, bi = idx - ti*NBt;
    size_t bo = (size_t)bi*DD*DD;
    int i = (bid & 63)*256 + t;
    int k = i >> 7, n = i & 127;
    float x;
    if (wf32) x = ((const float*)W.p[ti])[bo + i];
    else      x = b2f(((const unsigned short*)W.p[ti])[bo + i]);
    stage[(size_t)idx*DD*DD + n*DD + k] = f2b(x);
    return;
  }
  int i = blk*256 + t;
  bool big = (i < nB*16);
  int i2 = big ? i : (i - nB*16);
  if (!big && i2 >= nM*16) return;
  int r = i2>>4, c = (i2&15)*8;
  int vr = big ? valsB[r] : valsM[r];
  float vb[8];
  if (wf32){
    float4 f0 = *(const float4*)((const float*)emb + (size_t)vr*DD + c);
    float4 f1 = *(const float4*)((const float*)emb + (size_t)vr*DD + c + 4);
    vb[0]=f0.x; vb[1]=f0.y; vb[2]=f0.z; vb[3]=f0.w;
    vb[4]=f1.x; vb[5]=f1.y; vb[6]=f1.z; vb[7]=f1.w;
  } else {
    uint4 raw = *(const uint4*)((const unsigned short*)emb + (size_t)vr*DD + c);
    const unsigned short* hw = (const unsigned short*)&raw;
#pragma unroll
    for (int j=0;j<8;j++) vb[j] = b2f(hw[j]);
  }
  if (big){
    unsigned short* d = featB + (size_t)r*DD + c;
    us4 o0, o1;
    o0.x=f2b(vb[0]); o0.y=f2b(vb[1]); o0.z=f2b(vb[2]); o0.w=f2b(vb[3]);
    o1.x=f2b(vb[4]); o1.y=f2b(vb[5]); o1.z=f2b(vb[6]); o1.w=f2b(vb[7]);
    *(us4*)d = o0; *(us4*)(d+4) = o1;
  } else {
    float* d = featM + (size_t)r*DD + c;
    *(float4*)d     = make_float4(vb[0],vb[1],vb[2],vb[3]);
    *(float4*)(d+4) = make_float4(vb[4],vb[5],vb[6],vb[7]);
  }
}

// ---------------- merged CSR build (big + meta graphs) ----------------
__global__ __launch_bounds__(256) void k_hist2(
    const int* __restrict__ dstB, const int* __restrict__ dstM,
    int* __restrict__ degB, int* __restrict__ degM, int E, int ME, int nbE){
  int b = blockIdx.x, t = threadIdx.x;
  if (b < nbE){ int i = b*256+t; if (i < E) atomicAdd(&degB[dstB[i]], 1); }
  else { int i = (b-nbE)*256+t; if (i < ME) atomicAdd(&degM[dstM[i]], 1); }
}

__global__ __launch_bounds__(256) void k_scan1b(
    const int* __restrict__ degB, int* __restrict__ rpB, int* __restrict__ bsB,
    int nB, int nbB,
    const int* __restrict__ degM, int* __restrict__ rpM, int* __restrict__ bsM,
    int nM){
  __shared__ int ls[256];
  int blk = blockIdx.x, t = threadIdx.x;
  const int* deg; int* rowptr; int* bsum; int n; int b;
  if (blk < nbB){ deg=degB; rowptr=rpB; bsum=bsB; n=nB; b=blk; }
  else          { deg=degM; rowptr=rpM; bsum=bsM; n=nM; b=blk-nbB; }
  int base = b*1024 + t*4;
  int v0 = (base+0<n)?deg[base+0]:0;
  int v1 = (base+1<n)?deg[base+1]:0;
  int v2 = (base+2<n)?deg[base+2]:0;
  int v3 = (base+3<n)?deg[base+3]:0;
  int tsum = v0+v1+v2+v3;
  ls[t] = tsum; __syncthreads();
  for (int o=1;o<256;o<<=1){
    int x = (t>=o) ? ls[t-o] : 0;
    __syncthreads();
    ls[t] += x;
    __syncthreads();
  }
  int excl = ls[t]-tsum;
  if (t==255) bsum[b] = ls[255];
  if (base+0<n) rowptr[base+0]=excl;
  if (base+1<n) rowptr[base+1]=excl+v0;
  if (base+2<n) rowptr[base+2]=excl+v0+v1;
  if (base+3<n) rowptr[base+3]=excl+v0+v1+v2;
}

// scan3 with in-block prefix of block sums (scan2 merged in).
__global__ __launch_bounds__(256) void k_scan3b(
    int* __restrict__ rpB, const int* __restrict__ bsB, int* __restrict__ curB,
    int nB, int nb3B, int nbsB,
    int* __restrict__ rpM, const int* __restrict__ bsM, int* __restrict__ curM,
    int nM, int nbsM){
  __shared__ int spre;
  int blk = blockIdx.x, t = threadIdx.x;
  if (blk < nb3B){
    if (t == 0){
      int chunk = blk >> 2;
      int pre = 0;
      for (int j=0;j<chunk;j++) pre += bsB[j];
      spre = pre;
      if (blk == 0){
        int tot = 0;
        for (int j=0;j<nbsB;j++) tot += bsB[j];
        rpB[nB] = tot;
      }
    }
    __syncthreads();
    int i = blk*256 + t;
    if (i < nB){ int r = rpB[i] + spre; rpB[i] = r; curB[i] = r; }
  } else {
    int b2 = blk - nb3B;
    if (t == 0){
      int chunk = b2 >> 2;
      int pre = 0;
      for (int j=0;j<chunk;j++) pre += bsM[j];
      spre = pre;
      if (b2 == 0){
        int tot = 0;
        for (int j=0;j<nbsM;j++) tot += bsM[j];
        rpM[nM] = tot;
      }
    }
    __syncthreads();
    int i = b2*256 + t;
    if (i < nM){ int r = rpM[i] + spre; rpM[i] = r; curM[i] = r; }
  }
}

// scatter. Big graph: pack (src | meid<<17) into one int.
// Extra final block: target -> node chain (tgt_of/tgt_next) for fused readout.
__global__ __launch_bounds__(256) void k_scatter2(
    const int* __restrict__ dstB, const int* __restrict__ srcB,
    const int* __restrict__ auxB, int* __restrict__ curB,
    int* __restrict__ epackB, int E, int nbE,
    const int* __restrict__ dstM, const int* __restrict__ srcM,
    int* __restrict__ curM, int* __restrict__ esrcM, int* __restrict__ eauxM,
    int ME, int nbME,
    const int* __restrict__ tgt, int* __restrict__ tgt_of,
    int* __restrict__ tgt_next, int BT){
  int blk = blockIdx.x, t = threadIdx.x;
  if (blk < nbE){
    int e = blk*256 + t;
    if (e < E){
      int p = atomicAdd(&curB[dstB[e]], 1);
      epackB[p] = srcB[e] | (auxB[e] << 17);
    }
  } else if (blk < nbE + nbME){
    int e = (blk-nbE)*256 + t;
    if (e < ME){
      int p = atomicAdd(&curM[dstM[e]], 1);
      esrcM[p] = srcM[e];
      eauxM[p] = e;
    }
  } else {
    for (int i=t; i<BT; i+=256){
      int old = atomicExch(&tgt_of[tgt[i]], i);
      tgt_next[i] = old;
    }
  }
}

// ---------------- meta-graph edges: CSR, atomic-free, writes mef ----------------
// ONE WAVE PER (node, 64-channel half): heads 0-3 / 4-7 are independent
// softmax groups -> 2x wave parallelism, half the per-wave serial chain
// (was 3.9 waves/CU — latency-starved). agg PRE-NORMALIZED.
__global__ __launch_bounds__(256) void edge_meta_csr(
    const int* __restrict__ rowptr, const int* __restrict__ esrc,
    const int* __restrict__ eorig,
    const unsigned short* __restrict__ qm, const unsigned short* __restrict__ kfm,
    const unsigned short* __restrict__ vm,
    const float* __restrict__ base, unsigned short* __restrict__ mef,
    float* __restrict__ agg, int NM)
{
  int id = blockIdx.x*4 + (threadIdx.x>>6);
  int d = id >> 1, half = id & 1;
  if (d >= NM) return;
  int lane = threadIdx.x & 63;
  int off = half*64 + lane;
  const float* be2 = base+152; const float* be1 = base+16; const float* bn1 = base+8;
  size_t dq = (size_t)d*DD;
  float q0 = b2f(qm[dq+off]);
  float w0 = be2[off];
  int h = half*4 + (lane>>4);
  float bias = be1[h] + bn1[h];
  float z0=0.f, a0=0.f;
  int i0 = rowptr[d], i1 = rowptr[d+1];
  for (int i=i0; i<i1; i++){
    int s = esrc[i], e = eorig[i];
    size_t so=(size_t)s*DD, eo=(size_t)e*DD;
    float ke0 = b2f(kfm[so+off]) * w0;
    mef[eo+off]=f2b(ke0);
    float p0 = q0*ke0;
#pragma unroll
    for (int m=1;m<16;m<<=1) p0 += __shfl_xor(p0,m,64);
    float e0 = __expf(p0*0.25f + bias);
    z0 += e0;
    a0 += e0*b2f(vm[so+off]);
  }
  agg[dq+off] = a0 / (z0 + 1e-9f);
}

// Fused meta-learner over [agg_m (Ma node rows) | mef (bf16 edge rows)].
// Node rows ALSO fold the meta-Wo GEMM: x = relu(agg_m @ WoT) computed in f32
// (f32 dot, more precise than the old bf16-MFMA path), meta_feat += x in-place,
// and x feeds the learner directly (meta_out buffer eliminated).
// Node rows write COMBINED bf16 q-scale qsc = base_n2 + p2.
// 4 rows per block; u/W2/W1 columns cached in registers across rows.
__global__ __launch_bounds__(128) void learner2(
    const float* __restrict__ Xa, const unsigned short* __restrict__ Xb,
    int Ma, int Mtot,
    const void* __restrict__ u, const void* __restrict__ W2,
    const void* __restrict__ W1,
    const unsigned short* __restrict__ WoT, float* __restrict__ mfeat,
    unsigned short* __restrict__ qsc, float* __restrict__ p1a,
    unsigned short* __restrict__ w2me, unsigned short* __restrict__ p1b,
    const float* __restrict__ base, const int* __restrict__ dflag)
{
  __shared__ float sX[128];
  __shared__ float sAgg[128];
  __shared__ float st[16];
  __shared__ float sw[16];
  const bool wf32 = (*dflag) != 0;
  const int t = threadIdx.x;
  const int l = t>>3, j = t&7;
  float uc[16], w2c[16], w1c[16];
#pragma unroll
  for (int m=0;m<16;m++) uc[m] = gld(u, (size_t)l*128 + j*16 + m, wf32);
#pragma unroll
  for (int i=0;i<16;i++) w2c[i] = gld(W2, (size_t)i*128 + t, wf32);
  if (t < 8){
#pragma unroll
    for (int i=0;i<16;i++) w1c[i] = gld(W1, (size_t)i*8 + t, wf32);
  }
  for (int rr=0; rr<4; rr++){
    int row = blockIdx.x*4 + rr;
    if (row >= Mtot) break;
    const bool isB = (row >= Ma);
    const int m = isB ? (row - Ma) : row;
    if (isB) sX[t] = b2f(Xb[(size_t)m*DD + t]);
    else     sAgg[t] = Xa[(size_t)m*DD + t];
    __syncthreads();
    if (!isB){
      const unsigned short* wrow = WoT + (size_t)t*DD;
      float s = 0.f;
      for (int kk=0; kk<128; kk+=8){
        us8 wv = *(const us8*)(wrow + kk);
#pragma unroll
        for (int jj=0;jj<8;jj++) s += sAgg[kk+jj]*b2f(wv.s[jj]);
      }
      float r = fmaxf(s, 0.f);
      mfeat[(size_t)m*DD + t] += r;     // residual in-place
      sX[t] = r;
    }
    __syncthreads();
    float part = 0.f;
#pragma unroll
    for (int mm=0;mm<16;mm++) part += sX[j*16+mm]*uc[mm];
    part += __shfl_xor(part,1,64); part += __shfl_xor(part,2,64); part += __shfl_xor(part,4,64);
    if (j==0) st[l] = part * 0.08838834764831845f;
    __syncthreads();
    float mx=-1e30f;
    for (int i=0;i<16;i++) mx = fmaxf(mx, st[i]);
    float ssum=0.f;
    for (int i=0;i<16;i++) ssum += __expf(st[i]-mx);
    float inv = 1.f/ssum;
    if (t<16) sw[t] = __expf(st[t]-mx)*inv;
    __syncthreads();
    float a=0.f;
#pragma unroll
    for (int i=0;i<16;i++) a += sw[i]*w2c[i];
    if (isB) w2me[(size_t)m*DD+t] = f2b(base[152+t] + a);
    else     qsc [(size_t)m*DD+t] = f2b(base[24+t] + a);
    if (t<8){
      float bb=0.f;
#pragma unroll
      for (int i=0;i<16;i++) bb += sw[i]*w1c[i];
      if (isB) p1b[(size_t)m*HH+t] = f2b(bb);
      else     p1a[(size_t)m*HH+t] = bb;
    }
    __syncthreads();
  }
}

// ---------------- big-graph: fused scores+agg, fp8 kv, packed indices ----------
// Best measured form: one 16-lane group per dst node, natural order, node-major
// 256B kv rows fully consumed; q head-scale via pre-combined bf16 qsc (16B/lane,
// halves the scale-gather bytes vs f32). agg PRE-NORMALIZED (0.125 fp8
// v-descale folded into 1/z).
__global__ __launch_bounds__(256) void edge_fused(
    const int* __restrict__ rowptr, const int* __restrict__ epack,
    const int* __restrict__ mnid,
    const unsigned short* __restrict__ q, const unsigned char* __restrict__ kv8,
    const unsigned short* __restrict__ w2me, const unsigned short* __restrict__ p1me,
    const float* __restrict__ p1mn, const unsigned short* __restrict__ qsc,
    const float* __restrict__ base,
    unsigned short* __restrict__ aggb, int N)
{
  int wv = blockIdx.x*4 + (threadIdx.x>>6);
  int lane = threadIdx.x & 63;
  int grp = lane >> 4, l16 = lane & 15;
  int d = wv*4 + grp;                 // each 16-lane group owns one dst node
  if (d >= N) return;
  int c8 = l16 * 8;
  int h = l16 >> 1;

  int i0 = rowptr[d], i1 = rowptr[d+1];
  int mn = mnid[d];
  float bias = base[16+h] + base[8+h] + p1mn[(size_t)mn*HH + h];
  size_t dq = (size_t)d*DD;
  float qv[8];
  {
    uint4 qraw = *(const uint4*)(q + dq + c8);
    us8 sc = *(const us8*)(qsc + (size_t)mn*DD + c8);
    const unsigned short* qh = (const unsigned short*)&qraw;
#pragma unroll
    for (int j=0;j<8;j++) qv[j] = b2f(qh[j]) * b2f(sc.s[j]) * 0.03125f; // 0.25/8
  }

  float zh = 0.f;
  float a[8];
#pragma unroll
  for (int j=0;j<8;j++) a[j] = 0.f;

  int i = i0;
  for (; i + 1 < i1; i += 2){
    unsigned int v0p = (unsigned int)epack[i];
    unsigned int v1p = (unsigned int)epack[i+1];
    int s0 = v0p & 0x1FFFF, me0 = v0p >> 17;
    int s1 = v1p & 0x1FFFF, me1 = v1p >> 17;
    const unsigned char* kv0 = kv8 + (size_t)s0*256 + c8;
    const unsigned char* kv1 = kv8 + (size_t)s1*256 + c8;
    uint2 kraw0 = *(const uint2*)kv0;
    uint2 vraw0 = *(const uint2*)(kv0 + 128);
    uint4 wraw0 = *(const uint4*)(w2me + (size_t)me0*DD + c8);
    float pm0 = b2f(p1me[(size_t)me0*HH + h]);
    uint2 kraw1 = *(const uint2*)kv1;
    uint2 vraw1 = *(const uint2*)(kv1 + 128);
    uint4 wraw1 = *(const uint4*)(w2me + (size_t)me1*DD + c8);
    float pm1 = b2f(p1me[(size_t)me1*HH + h]);
    float k0f[8], v0f[8], k1f[8], v1f[8];
    cvt4(kraw0.x, k0f); cvt4(kraw0.y, k0f+4);
    cvt4(vraw0.x, v0f); cvt4(vraw0.y, v0f+4);
    cvt4(kraw1.x, k1f); cvt4(kraw1.y, k1f+4);
    cvt4(vraw1.x, v1f); cvt4(vraw1.y, v1f+4);
    const unsigned short* wh0 = (const unsigned short*)&wraw0;
    const unsigned short* wh1 = (const unsigned short*)&wraw1;
    float pA = 0.f, pB = 0.f;
#pragma unroll
    for (int j=0;j<8;j++){
      pA += qv[j]*(k0f[j]*b2f(wh0[j]));
      pB += qv[j]*(k1f[j]*b2f(wh1[j]));
    }
    pA += __shfl_xor(pA, 1, 64);
    pB += __shfl_xor(pB, 1, 64);
    float ex0 = __expf(pA + bias + pm0);
    float ex1 = __expf(pB + bias + pm1);
    zh += ex0 + ex1;
#pragma unroll
    for (int j=0;j<8;j++) a[j] += ex0*v0f[j] + ex1*v1f[j];
  }
  if (i < i1){
    unsigned int vp = (unsigned int)epack[i];
    int s = vp & 0x1FFFF, me = vp >> 17;
    const unsigned char* kv = kv8 + (size_t)s*256 + c8;
    uint2 kraw = *(const uint2*)kv;
    uint2 vraw = *(const uint2*)(kv + 128);
    uint4 wraw = *(const uint4*)(w2me + (size_t)me*DD + c8);
    float pm = b2f(p1me[(size_t)me*HH + h]);
    float kf[8], vf[8];
    cvt4(kraw.x, kf); cvt4(kraw.y, kf+4);
    cvt4(vraw.x, vf); cvt4(vraw.y, vf+4);
    const unsigned short* wh = (const unsigned short*)&wraw;
    float p = 0.f;
#pragma unroll
    for (int j=0;j<8;j++) p += qv[j]*(kf[j]*b2f(wh[j]));
    p += __shfl_xor(p, 1, 64);
    float ex = __expf(p + bias + pm);
    zh += ex;
#pragma unroll
    for (int j=0;j<8;j++) a[j] += ex*vf[j];
  }

  // each lane owns its 8 channels; zh is per-head (same in both pair lanes)
  float inv = 0.125f / (zh + 1e-9f);   // fp8 v-descale folded into 1/z
  us8 o;
#pragma unroll
  for (int j=0;j<8;j++) o.s[j] = f2b(a[j]*inv);
  *(us8*)(aggb + dq + c8) = o;
}

// final: out = acc * invNB (readout accumulated in gemm_wo epilogues)
__global__ __launch_bounds__(256) void k_finish(
    const float* __restrict__ acc, void* __restrict__ out,
    float invNB, int BT, const int* __restrict__ dflag)
{
  int t = blockIdx.x*256 + threadIdx.x;
  if (t >= BT) return;
  float r = acc[t] * invNB;
  if ((*dflag) != 0) ((float*)out)[t] = r;
  else ((__hip_bfloat16*)out)[t] = __float2bfloat16(r);
}

extern "C" void kernel_launch(void* const* d_in, const int* in_sizes, int n_in,
                              void* d_out, int out_size, void* d_ws, size_t ws_size,
                              hipStream_t stream) {
  const void* emb   = d_in[0];
  const void* u     = d_in[1];
  const void* W2lat = d_in[2];
  const void* W1lat = d_in[3];
  WPtrs wptrs;
  for (int i=0;i<8;i++) wptrs.p[i] = d_in[4+i];
  const int* node_vals      = (const int*)d_in[12];
  const int* meta_node_vals = (const int*)d_in[13];
  const int* src            = (const int*)d_in[14];
  const int* dst            = (const int*)d_in[15];
  const int* meta_src       = (const int*)d_in[16];
  const int* meta_dst       = (const int*)d_in[17];
  const int* meta_node_id   = (const int*)d_in[18];
  const int* meta_edge_id   = (const int*)d_in[19];
  const int* target_idx     = (const int*)d_in[20];
  const int* static_vals    = (const int*)d_in[21];
  const int* static_src     = (const int*)d_in[22];
  const int* static_dst     = (const int*)d_in[23];

  const int N  = in_sizes[12];
  const int MN = in_sizes[13];
  const int E  = in_sizes[14];
  const int ME = in_sizes[16];
  const int BT = in_sizes[20];
  const int NSRC = in_sizes[22];
  const int NB = in_sizes[8] / (DD*DD);

  float* ws = (float*)d_ws;
  size_t off = 0;
  // keep every allocation 16B-aligned (global_load_lds sources need it)
  auto allocf = [&](size_t n){ float* p = ws + off; off += (n + 3) & ~(size_t)3; return p; };
  auto allocb = [&](size_t n){ unsigned short* p = (unsigned short*)(ws + off); off += (((n+1)/2) + 3) & ~(size_t)3; return p; };
  auto alloci = [&](size_t n){ int* p = (int*)(ws + off); off += (n + 3) & ~(size_t)3; return p; };
  int*            dflag = (int*)ws; off += 4;
  unsigned short* feat  = allocb((size_t)N*DD);
  unsigned short* q     = allocb((size_t)N*DD);
  unsigned char*  kv8   = (unsigned char*)allocf((size_t)N*64);  // N x 256B fp8 rows
  unsigned short* aggb  = allocb((size_t)N*DD);
  float*          meta_feat= allocf((size_t)MN*DD);
  float*          agg_m = allocf((size_t)MN*DD);
  unsigned short* q_m   = allocb((size_t)MN*DD);
  unsigned short* kf_m  = allocb((size_t)MN*DD);
  unsigned short* v_m   = allocb((size_t)MN*DD);
  unsigned short* mef   = allocb((size_t)ME*DD);
  unsigned short* qsc   = allocb((size_t)MN*DD);   // bf16 combined q-scale
  float*          p1mn  = allocf((size_t)MN*HH);
  unsigned short* w2me  = allocb((size_t)ME*DD);
  unsigned short* p1me  = allocb((size_t)ME*HH);
  float*          base  = allocf(280);
  float*          acc   = allocf((size_t)BT);
  unsigned short* wstage= allocb((size_t)8*NB*DD*DD);
  int*            rowptr= alloci((size_t)N+1);
  int*            cursor= alloci((size_t)N);
  int*            epack = alloci((size_t)E);
  int*            rowptr_m= alloci((size_t)MN+1);
  int*            cursor_m= alloci((size_t)MN);
  int*            esrc_m  = alloci((size_t)ME);
  int*            eorig_m = alloci((size_t)ME);
  int*            degAll  = alloci((size_t)(N+MN));
  int*            deg     = degAll;
  int*            deg_m   = degAll + N;
  int*            tgt_of  = alloci((size_t)N);
  int*            tgt_next= alloci((size_t)BT);
  const int nb_scan   = (N + 1023)/1024;
  const int nb_scan_m = (MN + 1023)/1024;
  int*            bsum   = alloci((size_t)nb_scan);
  int*            bsum_m = alloci((size_t)nb_scan_m);
  (void)ws_size; (void)n_in; (void)out_size;

  const float* base_n2 = base + 24;

  const int nInit = (N + MN + 255)/256;
  const int gB = ((N+MN)*16+255)/256;
  k_setup<<<1 + nInit + gB + 8*NB*64,256,0,stream>>>(
      emb, static_vals, static_src, static_dst, u, W2lat, W1lat, base, NSRC,
      dflag, degAll, N+MN, tgt_of, N, acc, BT,
      node_vals, feat, N, meta_node_vals, meta_feat, MN,
      wptrs, wstage, NB, nInit, gB);

  const int nbE  = (E+255)/256, nbME = (ME+255)/256;
  const int nb3B = (N+255)/256, nb3M = (MN+255)/256;
  k_hist2<<<nbE+nbME,256,0,stream>>>(dst, meta_dst, deg, deg_m, E, ME, nbE);
  k_scan1b<<<nb_scan+nb_scan_m,256,0,stream>>>(deg, rowptr, bsum, N, nb_scan,
      deg_m, rowptr_m, bsum_m, MN);
  k_scan3b<<<nb3B+nb3M,256,0,stream>>>(rowptr, bsum, cursor, N, nb3B, nb_scan,
      rowptr_m, bsum_m, cursor_m, MN, nb_scan_m);
  k_scatter2<<<nbE+nbME+1,256,0,stream>>>(dst, src, meta_edge_id, cursor,
      epack, E, nbE, meta_dst, meta_src, cursor_m, esrc_m, eorig_m, ME, nbME,
      target_idx, tgt_of, tgt_next, BT);

  const int gm = (MN+63)/64;
  const int gN = (N+63)/64;
  const float invNB = 1.0f/(float)NB;

  for (int b=0;b<NB;b++){
    const unsigned short* wq_m = wstage + (size_t)(0*NB+b)*DD*DD;
    const unsigned short* wk_m = wstage + (size_t)(1*NB+b)*DD*DD;
    const unsigned short* wv_m = wstage + (size_t)(2*NB+b)*DD*DD;
    const unsigned short* wo_m = wstage + (size_t)(3*NB+b)*DD*DD;
    const unsigned short* wqb  = wstage + (size_t)(4*NB+b)*DD*DD;
    const unsigned short* wkb  = wstage + (size_t)(5*NB+b)*DD*DD;
    const unsigned short* wvb  = wstage + (size_t)(6*NB+b)*DD*DD;
    const unsigned short* wob  = wstage + (size_t)(7*NB+b)*DD*DD;

    // ---- merged big+meta QKV (big q plain; scale deferred to edge_fused) ----
    gemm_qkv2<<<gN+gm,256,0,stream>>>(feat, meta_feat,
        wqb, wkb, wvb, wq_m, wk_m, wv_m,
        q, kv8, q_m, kf_m, v_m, N, MN, gN, base_n2);

    // ---- meta conv (CSR, atomic-free; head-half split for 2x parallelism) ----
    edge_meta_csr<<<(2*MN+3)/4,256,0,stream>>>(rowptr_m, esrc_m, eorig_m,
        q_m, kf_m, v_m, base, mef, agg_m, MN);
    // learners (MN node rows incl. folded meta-Wo + residual; ME edge rows)
    learner2<<<(MN+ME+3)/4,128,0,stream>>>(agg_m, mef, MN, MN+ME,
        u, W2lat, W1lat, wo_m, meta_feat,
        qsc, p1mn, w2me, p1me, base, dflag);

    // ---- big conv (bf16 qsc head-scale; minimal-bytes kv layout) ----
    edge_fused<<<(N+15)/16,256,0,stream>>>(rowptr, epack,
        meta_node_id, q, kv8, w2me, p1me, p1mn, qsc, base, aggb, N);
    // big Wo + residual + FUSED READOUT into acc
    gemm_wo<<<gN,256,0,stream>>>(aggb, wob, feat, N,
        feat, meta_node_id, p1mn, base, tgt_of, tgt_next, acc);
  }
  k_finish<<<(BT+255)/256,256,0,stream>>>(acc, d_out, invNB, BT, dflag);
}